// Round 5
// baseline (439.998 us; speedup 1.0000x reference)
//
#include <hip/hip_runtime.h>

#define DELTA 1e-6f

// sizes: b=64, m=1024, w=64, r=4, d=512, iface=471
#define NB 64
#define NM 1024
#define NW 64
#define NR 4
#define ND 512
#define NIF 471
#define CTILE 256
#define RTILE 256

__device__ __forceinline__ float sigmoidf_(float x){ return 1.0f/(1.0f+expf(-x)); }
__device__ __forceinline__ float softplusf_(float x){ return fmaxf(x,0.0f) + log1pf(expf(-fabsf(x))); }

__device__ __forceinline__ float waveSum(float v){
  #pragma unroll
  for(int o=32;o>0;o>>=1) v += __shfl_down(v,o,64);
  return v;
}
__device__ __forceinline__ float waveMax(float v){
  #pragma unroll
  for(int o=32;o>0;o>>=1) v = fmaxf(v, __shfl_down(v,o,64));
  return v;
}
// DPP quad_perm xor-1 / xor-2 (VALU pipe, no LDS)
__device__ __forceinline__ float dpp_xor1(float x){
  int p = __builtin_amdgcn_update_dpp(0, __float_as_int(x), 0xB1, 0xF, 0xF, true);
  return __int_as_float(p);
}
__device__ __forceinline__ float dpp_xor2(float x){
  int p = __builtin_amdgcn_update_dpp(0, __float_as_int(x), 0x4E, 0xF, 0xF, true);
  return __int_as_float(p);
}

// ---------------- K1: iface = xi @ W + bW ----------------
__global__ __launch_bounds__(256) void k_iface(const float* __restrict__ xi,
                                               const float* __restrict__ Wm,
                                               const float* __restrict__ bW,
                                               float* __restrict__ iface){
  int b = blockIdx.x;
  __shared__ float xs[ND];
  for(int k=threadIdx.x;k<ND;k+=256) xs[k]=xi[b*ND+k];
  __syncthreads();
  for(int c=threadIdx.x;c<NIF;c+=256){
    float acc = bW[c];
    #pragma unroll 4
    for(int k=0;k<ND;k++) acc = fmaf(xs[k], Wm[k*NIF+c], acc);
    iface[b*NIF+c]=acc;
  }
}

// ---------------- K2: usage/psi, write-content softmax, allocation (sort), new_write_w ----------------
__global__ __launch_bounds__(1024) void k_write(
    const float* __restrict__ iface, const float* __restrict__ mem,
    const float* __restrict__ rw_old, const float* __restrict__ ww_old,
    const float* __restrict__ uv, float* __restrict__ wwp){
  int b = blockIdx.x; int tid = threadIdx.x;
  int lane = tid & 63, wv = tid >> 6;
  __shared__ float wkey[NW];
  __shared__ unsigned long long skey[NM];
  __shared__ float fb[NM];
  __shared__ float fb2[NM];
  __shared__ float red[17];
  const float* ifb = iface + b*NIF;
  if (tid < NW) wkey[tid] = ifb[260+tid];
  __syncthreads();
  float sw = softplusf_(1.0f + fmaxf(ifb[324],0.0f));
  float ag = sigmoidf_(ifb[457]);
  float wg = sigmoidf_(ifb[458]);
  float fg0=sigmoidf_(ifb[453]), fg1=sigmoidf_(ifb[454]);
  float fg2=sigmoidf_(ifb[455]), fg3=sigmoidf_(ifb[456]);
  float kn=0.0f;
  for(int k=0;k<NW;k++){ float t=wkey[k]; kn += t*t; }
  kn = sqrtf(kn);
  int j = tid;
  float u0  = uv[b*NM+j];
  float wwo = ww_old[b*NM+j];
  float usage = u0 + (1.0f-u0)*(1.0f - (1.0f-wwo));
  float psi = (1.0f - fg0*rw_old[(b*NR+0)*NM+j])
            * (1.0f - fg1*rw_old[(b*NR+1)*NM+j])
            * (1.0f - fg2*rw_old[(b*NR+2)*NM+j])
            * (1.0f - fg3*rw_old[(b*NR+3)*NM+j]);
  usage *= psi;
  float dot=0.0f, nrm=0.0f;
  const float* mrow = mem + ((size_t)b*NM + j)*NW;
  for(int k=0;k<NW;k++){ float mv=mrow[k]; dot = fmaf(mv,wkey[k],dot); nrm = fmaf(mv,mv,nrm); }
  float logit = sw * dot / ((sqrtf(nrm)+DELTA)*(kn+DELTA));
  float m1 = waveMax(logit); if(lane==0) red[wv]=m1; __syncthreads();
  if(tid==0){ float mm=red[0]; for(int i=1;i<16;i++) mm=fmaxf(mm,red[i]); red[16]=mm; } __syncthreads();
  float e = expf(logit - red[16]);
  float s1 = waveSum(e); if(lane==0) red[wv]=s1; __syncthreads();
  if(tid==0){ float ss=0; for(int i=0;i<16;i++) ss+=red[i]; red[16]=ss; } __syncthreads();
  float wcw = e/red[16];
  float u = DELTA + (1.0f-DELTA)*usage;
  skey[tid] = ((unsigned long long)__float_as_uint(u) << 32) | (unsigned)tid;
  __syncthreads();
  for(int k2=2;k2<=NM;k2<<=1){
    for(int jj=k2>>1;jj>0;jj>>=1){
      int ixj = tid ^ jj;
      if (ixj > tid){
        unsigned long long a=skey[tid], c=skey[ixj];
        bool asc = ((tid & k2)==0);
        bool doswap = asc ? (a>c) : (a<c);
        if (doswap){ skey[tid]=c; skey[ixj]=a; }
      }
      __syncthreads();
    }
  }
  float su = __uint_as_float((unsigned)(skey[tid]>>32));
  int phi  = (int)(skey[tid] & 0xffffffffu);
  fb[tid] = su; __syncthreads();
  for(int d=1; d<NM; d<<=1){
    float o = (tid>=d)? fb[tid-d] : 1.0f;
    __syncthreads();
    fb[tid] *= o;
    __syncthreads();
  }
  float salloc = (1.0f - su)*fb[tid];
  fb2[phi] = salloc;
  __syncthreads();
  float alloc = fb2[tid];
  wwp[b*NM+tid] = wg*(ag*alloc + (1.0f-ag)*wcw);
}

// ---------------- K3: one streaming pass over L ----------------
// Per block: 256 rows x 256 cols of L[b].
// RF[r,j] = (1-ww[j])*sum_n L[j,n]*rw[r,n] - sum_n L[j,n]*ww[n]*rw[r,n]   (atomicAdd)
// C2[r,n] = sum_m L[m,n]*rw[r,m];  C3[r,n] = sum_m L[m,n]*rw[r,m]*ww[m]  (atomicAdd)
// NOTE: __launch_bounds__(256, 2) is load-bearing. Live set ~130 VGPR (g/h 32 +
// c2a/c3a 32 + v[32] + Lc[16] + temps). Without an explicit bound hipcc assumes
// 1024-thread blocks and caps ~68 VGPR -> 3KB/thread scratch spill -> 845MB of
// HBM writes (rounds 3/4). (256,2) caps at 256 VGPR: no spill, >=2 waves/SIMD.
__global__ __launch_bounds__(256, 2) void k_link3(
    const float* __restrict__ link, const float* __restrict__ rw,
    const float* __restrict__ wwp,
    float* __restrict__ RF, float* __restrict__ C2, float* __restrict__ C3){
  int cx = blockIdx.x, ry = blockIdx.y, b = blockIdx.z;
  int tid = threadIdx.x, lane = tid&63, wv = tid>>6;
  __shared__ float s_gg[NR][RTILE];
  __shared__ float s_ww[RTILE];
  #pragma unroll
  for (int r=0;r<NR;r++) s_gg[r][tid] = rw[(b*NR+r)*NM + ry*RTILE + tid];
  s_ww[tid] = wwp[b*NM + ry*RTILE + tid];
  __syncthreads();
  int c0 = cx*CTILE + lane*4;
  // per-lane column weights (g = rw[r][col], h = g*ww[col])
  float g[NR][4], h[NR][4];
  float4 wwc4 = *(const float4*)(wwp + b*NM + c0);
  float wwc[4] = {wwc4.x, wwc4.y, wwc4.z, wwc4.w};
  #pragma unroll
  for (int r=0;r<NR;r++){
    float4 gv = *(const float4*)(rw + (b*NR+r)*NM + c0);
    g[r][0]=gv.x; g[r][1]=gv.y; g[r][2]=gv.z; g[r][3]=gv.w;
    #pragma unroll
    for (int e=0;e<4;e++) h[r][e] = g[r][e]*wwc[e];
  }
  float c2a[NR][4]={}, c3a[NR][4]={};
  const float* Lw = link + ((size_t)b<<20) + (size_t)(ry*RTILE + wv*64)*NM + c0;
  for (int grp=0; grp<16; ++grp){
    float4 Lc[4];
    #pragma unroll
    for (int rr=0;rr<4;rr++) Lc[rr] = *(const float4*)(Lw + (size_t)(grp*4+rr)*NM);
    int rl0 = wv*64 + grp*4;
    // v[row*8 + isB*4 + r]
    float v[32];
    #pragma unroll
    for (int i=0;i<32;i++) v[i]=0.0f;
    #pragma unroll
    for (int rr=0;rr<4;rr++){
      float le[4] = {Lc[rr].x, Lc[rr].y, Lc[rr].z, Lc[rr].w};
      float wwr = s_ww[rl0+rr];
      #pragma unroll
      for (int r=0;r<NR;r++){
        float ggr = s_gg[r][rl0+rr];
        float hhr = ggr*wwr;
        #pragma unroll
        for (int e=0;e<4;e++){
          c2a[r][e]   = fmaf(le[e], ggr,    c2a[r][e]);
          c3a[r][e]   = fmaf(le[e], hhr,    c3a[r][e]);
          v[rr*8+r]   = fmaf(le[e], g[r][e], v[rr*8+r]);
          v[rr*8+4+r] = fmaf(le[e], h[r][e], v[rr*8+4+r]);
        }
      }
    }
    // compact butterfly: lane ends with sum over all 64 lanes of v[lane&31]
    float w16[16];
    #pragma unroll
    for (int jj=0;jj<16;jj++){ w16[jj] = (lane&1)? v[2*jj+1] : v[2*jj]; }
    #pragma unroll
    for (int jj=0;jj<16;jj++) w16[jj] += dpp_xor1(w16[jj]);
    float w8[8];
    #pragma unroll
    for (int jj=0;jj<8;jj++){ w8[jj] = (lane&2)? w16[2*jj+1] : w16[2*jj]; }
    #pragma unroll
    for (int jj=0;jj<8;jj++) w8[jj] += dpp_xor2(w8[jj]);
    float w4a[4];
    #pragma unroll
    for (int jj=0;jj<4;jj++){ w4a[jj] = (lane&4)? w8[2*jj+1] : w8[2*jj]; }
    #pragma unroll
    for (int jj=0;jj<4;jj++) w4a[jj] += __shfl_xor(w4a[jj], 4, 64);
    float w2a[2];
    #pragma unroll
    for (int jj=0;jj<2;jj++){ w2a[jj] = (lane&8)? w4a[2*jj+1] : w4a[2*jj]; }
    #pragma unroll
    for (int jj=0;jj<2;jj++) w2a[jj] += __shfl_xor(w2a[jj], 8, 64);
    float w1 = (lane&16)? w2a[1] : w2a[0];
    w1 += __shfl_xor(w1, 16, 64);
    w1 += __shfl_xor(w1, 32, 64);
    float other = __shfl_xor(w1, 4, 64);   // partner has isB flipped
    int i5 = lane & 31;
    int rowIdx = i5>>3, r_ = i5&3, isB = (i5>>2)&1;
    if (!isB && lane < 32){
      int rl = rl0 + rowIdx;
      float wwj = s_ww[rl];
      float rf = fmaf(-wwj, w1, w1) - other;   // (1-wwj)*SumA - SumB
      atomicAdd(&RF[(b*NR + r_)*NM + ry*RTILE + rl], rf);
    }
  }
  #pragma unroll
  for (int r=0;r<NR;r++){
    #pragma unroll
    for (int e=0;e<4;e++){
      atomicAdd(&C2[(b*NR+r)*NM + c0+e], c2a[r][e]);
      atomicAdd(&C3[(b*NR+r)*NM + c0+e], c3a[r][e]);
    }
  }
}

// ---------------- K4: read-content softmax, forward/backward finalize, read_vectors ----------------
__global__ __launch_bounds__(1024) void k_read(
    const float* __restrict__ iface, const float* __restrict__ mem,
    const float* __restrict__ link, const float* __restrict__ prec,
    const float* __restrict__ rw_old, const float* __restrict__ wwp,
    const float* __restrict__ RF,
    const float* __restrict__ C2, const float* __restrict__ C3,
    float* __restrict__ out){
  int b = blockIdx.x; int tid = threadIdx.x; int lane=tid&63, wv=tid>>6;
  __shared__ float keys[NR][NW];
  __shared__ float er[NW], wvec[NW];
  __shared__ float wwb[NM];
  __shared__ float nrw[NR][NM];
  __shared__ float red[17];
  __shared__ float scal[16];   // [0..3]=Pr, [4..7]=Kr, [8..11]=keynorm, [12..15]=strength
  __shared__ float rm[NR][3];
  __shared__ float accb[16][NR][NW];
  const float* ifb = iface + b*NIF;
  if (tid < 256){ int r=tid>>6, k=tid&63; keys[r][k] = ifb[r*NW+k]; }
  if (tid >= 256 && tid < 320){ int k=tid-256; er[k]=sigmoidf_(ifb[325+k]); wvec[k]=ifb[389+k]; }
  wwb[tid] = wwp[b*NM+tid];
  if (tid == 0){
    for(int mo=0;mo<3;mo++){
      float x0=ifb[458+0*3+mo], x1=ifb[458+1*3+mo], x2=ifb[458+2*3+mo], x3=ifb[458+3*3+mo];
      float mx = fmaxf(fmaxf(x0,x1),fmaxf(x2,x3));
      float e0=expf(x0-mx),e1=expf(x1-mx),e2=expf(x2-mx),e3=expf(x3-mx);
      float s=e0+e1+e2+e3;
      rm[0][mo]=e0/s; rm[1][mo]=e1/s; rm[2][mo]=e2/s; rm[3][mo]=e3/s;
    }
  }
  __syncthreads();
  if (tid < NR){
    float knv=0; for(int k=0;k<NW;k++){ float t=keys[tid][k]; knv += t*t; }
    scal[8+tid]  = sqrtf(knv);
    scal[12+tid] = softplusf_(1.0f + fmaxf(ifb[256+tid],0.0f));
  }
  int j = tid;
  float pj  = prec[b*NM+j];
  float wwj = wwb[j];
  float rwv[NR];
  #pragma unroll
  for(int r=0;r<NR;r++) rwv[r]=rw_old[(b*NR+r)*NM+j];
  for(int q=0;q<8;q++){
    float v = (q<4)? pj*rwv[q] : wwj*rwv[q-4];
    float s = waveSum(v);
    if(lane==0) red[wv]=s;
    __syncthreads();
    if(tid==0){ float ss=0; for(int i=0;i<16;i++) ss+=red[i]; scal[q]=ss; }
    __syncthreads();
  }
  const float* mrow = mem + ((size_t)b*NM+j)*NW;
  float dots[NR]={0,0,0,0}; float nrm=0.0f;
  for(int k=0;k<NW;k++){
    float nmv = fmaf(mrow[k], (1.0f - wwj*er[k]), wwj*wvec[k]);
    nrm = fmaf(nmv,nmv,nrm);
    #pragma unroll
    for(int r=0;r<NR;r++) dots[r] = fmaf(nmv, keys[r][k], dots[r]);
  }
  float inv = 1.0f/(sqrtf(nrm)+DELTA);
  float cw[NR];
  for(int r=0;r<NR;r++){
    float logit = scal[12+r]*dots[r]*inv/(scal[8+r]+DELTA);
    float m1 = waveMax(logit); if(lane==0) red[wv]=m1; __syncthreads();
    if(tid==0){ float mm=red[0]; for(int i=1;i<16;i++) mm=fmaxf(mm,red[i]); red[16]=mm; } __syncthreads();
    float e = expf(logit - red[16]);
    float s1 = waveSum(e); if(lane==0) red[wv]=s1; __syncthreads();
    if(tid==0){ float ss=0; for(int i=0;i<16;i++) ss+=red[i]; red[16]=ss; } __syncthreads();
    cw[r] = e/red[16];
    __syncthreads();
  }
  float Ljj = link[((size_t)b<<20) + (size_t)j*(NM+1)];
  #pragma unroll
  for(int r=0;r<NR;r++){
    float F  = RF[(b*NR+r)*NM+j];
    float cc2 = C2[(b*NR+r)*NM+j], cc3 = C3[(b*NR+r)*NM+j];
    float grj = rwv[r];
    float fwd = F - Ljj*grj*(1.0f-2.0f*wwj) + wwj*(scal[r] - pj*grj);
    float bwd = (cc2 - cc3) - Ljj*grj*(1.0f-wwj) - wwj*(cc2 - Ljj*grj) + pj*(scal[4+r] - wwj*grj);
    nrw[r][j] = rm[r][0]*bwd + rm[r][1]*fwd + rm[r][2]*cw[r];
  }
  __syncthreads();
  int w = lane;
  float erw = er[w], wvw = wvec[w];
  float acc[NR]={0,0,0,0};
  int jbase = wv*64;
  for(int jj=0;jj<64;jj++){
    int jr = jbase+jj;
    float wwr = wwb[jr];
    float nmv = fmaf(mem[((size_t)b*NM+jr)*NW + w], (1.0f - wwr*erw), wwr*wvw);
    #pragma unroll
    for(int r=0;r<NR;r++) acc[r] = fmaf(nrw[r][jr], nmv, acc[r]);
  }
  #pragma unroll
  for(int r=0;r<NR;r++) accb[wv][r][w] = acc[r];
  __syncthreads();
  if (tid < 256){
    int r = tid>>6, k = tid&63;
    float s=0;
    for(int v=0;v<16;v++) s += accb[v][r][k];
    out[b*NR*NW + r*NW + k] = s;
  }
}

extern "C" void kernel_launch(void* const* d_in, const int* in_sizes, int n_in,
                              void* d_out, int out_size, void* d_ws, size_t ws_size,
                              hipStream_t stream) {
  (void)in_sizes; (void)n_in; (void)out_size; (void)ws_size;
  const float* xi   = (const float*)d_in[0];
  const float* Wm   = (const float*)d_in[1];
  const float* bW   = (const float*)d_in[2];
  const float* mem  = (const float*)d_in[3];
  const float* link = (const float*)d_in[4];
  const float* prec = (const float*)d_in[5];
  const float* rw   = (const float*)d_in[6];
  const float* wwo  = (const float*)d_in[7];
  const float* uv   = (const float*)d_in[8];
  float* out = (float*)d_out;
  float* ws  = (float*)d_ws;
  float* iface = ws;                 // 64*471 -> pad 30208
  float* wwp   = ws + 30208;         // 65536
  float* RF    = wwp + 65536;        // 262144
  float* C2    = RF + 262144;        // 262144
  float* C3    = C2 + 262144;        // 262144
  hipMemsetAsync(RF, 0, 3*262144*sizeof(float), stream);  // RF,C2,C3
  k_iface<<<NB, 256, 0, stream>>>(xi, Wm, bW, iface);
  k_write<<<NB, 1024, 0, stream>>>(iface, mem, rw, wwo, uv, wwp);
  k_link3<<<dim3(4, 4, NB), 256, 0, stream>>>(link, rw, wwp, RF, C2, C3);
  k_read<<<NB, 1024, 0, stream>>>(iface, mem, link, prec, rw, wwp, RF, C2, C3, out);
}

// Round 6
// 220.365 us; speedup vs baseline: 1.9967x; 1.9967x over previous
//
#include <hip/hip_runtime.h>

#define DELTA 1e-6f

// sizes: b=64, m=1024, w=64, r=4, d=512, iface=471
#define NB 64
#define NM 1024
#define NW 64
#define NR 4
#define ND 512
#define NIF 471

__device__ __forceinline__ float sigmoidf_(float x){ return 1.0f/(1.0f+expf(-x)); }
__device__ __forceinline__ float softplusf_(float x){ return fmaxf(x,0.0f) + log1pf(expf(-fabsf(x))); }

__device__ __forceinline__ float waveSum(float v){
  #pragma unroll
  for(int o=32;o>0;o>>=1) v += __shfl_down(v,o,64);
  return v;
}
__device__ __forceinline__ float waveMax(float v){
  #pragma unroll
  for(int o=32;o>0;o>>=1) v = fmaxf(v, __shfl_down(v,o,64));
  return v;
}

// ---------------- K1: iface = xi @ W + bW ----------------
__global__ __launch_bounds__(256) void k_iface(const float* __restrict__ xi,
                                               const float* __restrict__ Wm,
                                               const float* __restrict__ bW,
                                               float* __restrict__ iface){
  int b = blockIdx.x;
  __shared__ float xs[ND];
  for(int k=threadIdx.x;k<ND;k+=256) xs[k]=xi[b*ND+k];
  __syncthreads();
  for(int c=threadIdx.x;c<NIF;c+=256){
    float acc = bW[c];
    #pragma unroll 4
    for(int k=0;k<ND;k++) acc = fmaf(xs[k], Wm[k*NIF+c], acc);
    iface[b*NIF+c]=acc;
  }
}

// ---------------- K2: usage/psi, write-content softmax, allocation (sort), new_write_w ----------------
__global__ __launch_bounds__(1024) void k_write(
    const float* __restrict__ iface, const float* __restrict__ mem,
    const float* __restrict__ rw_old, const float* __restrict__ ww_old,
    const float* __restrict__ uv, float* __restrict__ wwp){
  int b = blockIdx.x; int tid = threadIdx.x;
  int lane = tid & 63, wv = tid >> 6;
  __shared__ float wkey[NW];
  __shared__ unsigned long long skey[NM];
  __shared__ float fb[NM];
  __shared__ float fb2[NM];
  __shared__ float red[17];
  const float* ifb = iface + b*NIF;
  if (tid < NW) wkey[tid] = ifb[260+tid];
  __syncthreads();
  float sw = softplusf_(1.0f + fmaxf(ifb[324],0.0f));
  float ag = sigmoidf_(ifb[457]);
  float wg = sigmoidf_(ifb[458]);
  float fg0=sigmoidf_(ifb[453]), fg1=sigmoidf_(ifb[454]);
  float fg2=sigmoidf_(ifb[455]), fg3=sigmoidf_(ifb[456]);
  float kn=0.0f;
  for(int k=0;k<NW;k++){ float t=wkey[k]; kn += t*t; }
  kn = sqrtf(kn);
  int j = tid;
  float u0  = uv[b*NM+j];
  float wwo = ww_old[b*NM+j];
  float usage = u0 + (1.0f-u0)*(1.0f - (1.0f-wwo));
  float psi = (1.0f - fg0*rw_old[(b*NR+0)*NM+j])
            * (1.0f - fg1*rw_old[(b*NR+1)*NM+j])
            * (1.0f - fg2*rw_old[(b*NR+2)*NM+j])
            * (1.0f - fg3*rw_old[(b*NR+3)*NM+j]);
  usage *= psi;
  float dot=0.0f, nrm=0.0f;
  const float* mrow = mem + ((size_t)b*NM + j)*NW;
  for(int k=0;k<NW;k++){ float mv=mrow[k]; dot = fmaf(mv,wkey[k],dot); nrm = fmaf(mv,mv,nrm); }
  float logit = sw * dot / ((sqrtf(nrm)+DELTA)*(kn+DELTA));
  float m1 = waveMax(logit); if(lane==0) red[wv]=m1; __syncthreads();
  if(tid==0){ float mm=red[0]; for(int i=1;i<16;i++) mm=fmaxf(mm,red[i]); red[16]=mm; } __syncthreads();
  float e = expf(logit - red[16]);
  float s1 = waveSum(e); if(lane==0) red[wv]=s1; __syncthreads();
  if(tid==0){ float ss=0; for(int i=0;i<16;i++) ss+=red[i]; red[16]=ss; } __syncthreads();
  float wcw = e/red[16];
  float u = DELTA + (1.0f-DELTA)*usage;
  skey[tid] = ((unsigned long long)__float_as_uint(u) << 32) | (unsigned)tid;
  __syncthreads();
  for(int k2=2;k2<=NM;k2<<=1){
    for(int jj=k2>>1;jj>0;jj>>=1){
      int ixj = tid ^ jj;
      if (ixj > tid){
        unsigned long long a=skey[tid], c=skey[ixj];
        bool asc = ((tid & k2)==0);
        bool doswap = asc ? (a>c) : (a<c);
        if (doswap){ skey[tid]=c; skey[ixj]=a; }
      }
      __syncthreads();
    }
  }
  float su = __uint_as_float((unsigned)(skey[tid]>>32));
  int phi  = (int)(skey[tid] & 0xffffffffu);
  fb[tid] = su; __syncthreads();
  for(int d=1; d<NM; d<<=1){
    float o = (tid>=d)? fb[tid-d] : 1.0f;
    __syncthreads();
    fb[tid] *= o;
    __syncthreads();
  }
  float salloc = (1.0f - su)*fb[tid];
  fb2[phi] = salloc;
  __syncthreads();
  float alloc = fb2[tid];
  wwp[b*NM+tid] = wg*(ag*alloc + (1.0f-ag)*wcw);
}

// ---------------- K3: one streaming pass over L (LDS-staged, reduction-free) ----------------
// Block tile: 256 rows x 256 cols, 4 chunks of 64 rows x 256 cols staged in LDS.
// RF[r,j] = sum_n L[j,n]*g[r,n]*(1 - ww[j] - ww[n])   (phase R: lane owns a row -> no cross-lane reduce)
// C2[r,n] = sum_m L[m,n]*g[r,m];  C3[r,n] = sum_m L[m,n]*g[r,m]*ww[m]   (phase C: lane owns 4 cols)
// LDS 74KB -> 2 blocks/CU; live set ~60 VGPR -> spill-proof at any allocator budget.
// (Rounds 3-5 lesson: small-LDS kernels get a high default occupancy target -> ~68 VGPR cap ->
//  3KB/thread scratch spill, 845MB HBM writes. Fix is structural, not launch_bounds.)
__global__ __launch_bounds__(256) void k_link4(
    const float* __restrict__ link, const float* __restrict__ rw,
    const float* __restrict__ wwp,
    float* __restrict__ RF, float* __restrict__ C2, float* __restrict__ C3){
  int cx = blockIdx.x, ry = blockIdx.y, b = blockIdx.z;
  int tid = threadIdx.x, lane = tid&63, wv = tid>>6;
  __shared__ float4 s_L4[4096];    // 64KB: 64 rows x 64 16B-blocks, blk ^= (row&7)
  __shared__ float4 s_gcol4[256];  // per col: {g0,g1,g2,g3}
  __shared__ float  s_mwc[256];    // 1 - ww[col]
  __shared__ float4 s_grow4[64];   // per row: {g0..g3}
  __shared__ float  s_wwr[64];     // ww[row]
  __shared__ float4 s_rfp4[256];   // phase-R partials [wave][row]
  const float* Lb = link + ((size_t)b<<20);
  int colbase = cx*256, rowbase = ry*256;
  // block-constant column weights
  {
    float g0 = rw[(b*NR+0)*NM + colbase + tid];
    float g1 = rw[(b*NR+1)*NM + colbase + tid];
    float g2 = rw[(b*NR+2)*NM + colbase + tid];
    float g3 = rw[(b*NR+3)*NM + colbase + tid];
    s_gcol4[tid] = make_float4(g0,g1,g2,g3);
    s_mwc[tid] = 1.0f - wwp[b*NM + colbase + tid];
  }
  float c2a[NR][4], c3a[NR][4];
  #pragma unroll
  for(int r=0;r<NR;r++){
    #pragma unroll
    for(int e=0;e<4;e++){ c2a[r][e]=0.0f; c3a[r][e]=0.0f; }
  }
  for (int ch=0; ch<4; ++ch){
    int rb = rowbase + ch*64;
    // stage row weights
    {
      int r = tid>>6, rl = tid&63;
      ((float*)s_grow4)[rl*4+r] = rw[(b*NR+r)*NM + rb + rl];
    }
    if (tid < 64) s_wwr[tid] = wwp[b*NM + rb + tid];
    // stage L chunk (coalesced 1KB/row loads, XOR-swizzled LDS write)
    #pragma unroll 4
    for (int j=0;j<16;j++){
      int rl = wv + 4*j;
      float4 lv = *(const float4*)(Lb + (size_t)(rb+rl)*NM + colbase + lane*4);
      s_L4[rl*64 + (lane ^ (rl&7))] = lv;
    }
    __syncthreads();
    // ---- phase R: lane = local row, wave covers cols [wv*64, wv*64+64) ----
    float wwj = s_wwr[lane];
    float rf[4] = {0,0,0,0};
    int lane7 = lane&7;
    #pragma unroll 2
    for (int cs=0; cs<16; cs++){
      int c = wv*64 + cs*4, cq = c>>2;
      float4 lv = s_L4[lane*64 + (cq ^ lane7)];
      float4 mw = *((const float4*)s_mwc + cq);
      float le[4] = {lv.x,lv.y,lv.z,lv.w};
      float mv[4] = {mw.x,mw.y,mw.z,mw.w};
      #pragma unroll
      for (int e=0;e<4;e++){
        float4 gv = s_gcol4[c+e];
        float ls = le[e]*(mv[e]-wwj);
        rf[0] = fmaf(ls, gv.x, rf[0]);
        rf[1] = fmaf(ls, gv.y, rf[1]);
        rf[2] = fmaf(ls, gv.z, rf[2]);
        rf[3] = fmaf(ls, gv.w, rf[3]);
      }
    }
    s_rfp4[wv*64+lane] = make_float4(rf[0],rf[1],rf[2],rf[3]);
    // ---- phase C: wave covers rows [wv*16, wv*16+16), lane owns 4 cols ----
    #pragma unroll 2
    for (int ri=0; ri<16; ri++){
      int row = wv*16 + ri;
      float4 lv = s_L4[row*64 + (lane ^ (row&7))];
      float4 gg = s_grow4[row];
      float wwr = s_wwr[row];
      float le[4] = {lv.x,lv.y,lv.z,lv.w};
      float ggv[4] = {gg.x,gg.y,gg.z,gg.w};
      float ggw[4];
      #pragma unroll
      for (int r=0;r<NR;r++) ggw[r] = ggv[r]*wwr;
      #pragma unroll
      for (int e=0;e<4;e++){
        #pragma unroll
        for (int r=0;r<NR;r++){
          c2a[r][e] = fmaf(le[e], ggv[r], c2a[r][e]);
          c3a[r][e] = fmaf(le[e], ggw[r], c3a[r][e]);
        }
      }
    }
    __syncthreads();
    // rf combine: 4 wave-partials -> 1 atomic per (row, r)
    {
      int row = tid>>2, r = tid&3;
      const float* rp = (const float*)s_rfp4;
      float s = rp[(0*64+row)*4+r] + rp[(1*64+row)*4+r]
              + rp[(2*64+row)*4+r] + rp[(3*64+row)*4+r];
      atomicAdd(&RF[(b*NR+r)*NM + rb + row], s);
    }
  }
  // ---- c2/c3 combine across waves (reuse s_L4), then 4-float atomic flush ----
  __syncthreads();
  float4* s_comb = s_L4;
  #pragma unroll
  for (int r=0;r<NR;r++){
    s_comb[(wv*64+lane)*8 + r]     = make_float4(c2a[r][0],c2a[r][1],c2a[r][2],c2a[r][3]);
    s_comb[(wv*64+lane)*8 + 4 + r] = make_float4(c3a[r][0],c3a[r][1],c3a[r][2],c3a[r][3]);
  }
  __syncthreads();
  for (int t=tid; t<512; t+=256){
    int lc = t>>3, q = t&7;
    float4 a = s_comb[(0*64+lc)*8+q];
    float4 bb= s_comb[(1*64+lc)*8+q];
    float4 c = s_comb[(2*64+lc)*8+q];
    float4 d = s_comb[(3*64+lc)*8+q];
    float sx=a.x+bb.x+c.x+d.x, sy=a.y+bb.y+c.y+d.y, sz=a.z+bb.z+c.z+d.z, sw=a.w+bb.w+c.w+d.w;
    float* dst = (q<4) ? &C2[(b*NR+q)*NM + colbase + lc*4]
                       : &C3[(b*NR+(q-4))*NM + colbase + lc*4];
    atomicAdd(dst+0, sx); atomicAdd(dst+1, sy); atomicAdd(dst+2, sz); atomicAdd(dst+3, sw);
  }
}

// ---------------- K4: read-content softmax, forward/backward finalize, read_vectors ----------------
__global__ __launch_bounds__(1024) void k_read(
    const float* __restrict__ iface, const float* __restrict__ mem,
    const float* __restrict__ link, const float* __restrict__ prec,
    const float* __restrict__ rw_old, const float* __restrict__ wwp,
    const float* __restrict__ RF,
    const float* __restrict__ C2, const float* __restrict__ C3,
    float* __restrict__ out){
  int b = blockIdx.x; int tid = threadIdx.x; int lane=tid&63, wv=tid>>6;
  __shared__ float keys[NR][NW];
  __shared__ float er[NW], wvec[NW];
  __shared__ float wwb[NM];
  __shared__ float nrw[NR][NM];
  __shared__ float red[17];
  __shared__ float scal[16];   // [0..3]=Pr, [4..7]=Kr, [8..11]=keynorm, [12..15]=strength
  __shared__ float rm[NR][3];
  __shared__ float accb[16][NR][NW];
  const float* ifb = iface + b*NIF;
  if (tid < 256){ int r=tid>>6, k=tid&63; keys[r][k] = ifb[r*NW+k]; }
  if (tid >= 256 && tid < 320){ int k=tid-256; er[k]=sigmoidf_(ifb[325+k]); wvec[k]=ifb[389+k]; }
  wwb[tid] = wwp[b*NM+tid];
  if (tid == 0){
    for(int mo=0;mo<3;mo++){
      float x0=ifb[458+0*3+mo], x1=ifb[458+1*3+mo], x2=ifb[458+2*3+mo], x3=ifb[458+3*3+mo];
      float mx = fmaxf(fmaxf(x0,x1),fmaxf(x2,x3));
      float e0=expf(x0-mx),e1=expf(x1-mx),e2=expf(x2-mx),e3=expf(x3-mx);
      float s=e0+e1+e2+e3;
      rm[0][mo]=e0/s; rm[1][mo]=e1/s; rm[2][mo]=e2/s; rm[3][mo]=e3/s;
    }
  }
  __syncthreads();
  if (tid < NR){
    float knv=0; for(int k=0;k<NW;k++){ float t=keys[tid][k]; knv += t*t; }
    scal[8+tid]  = sqrtf(knv);
    scal[12+tid] = softplusf_(1.0f + fmaxf(ifb[256+tid],0.0f));
  }
  int j = tid;
  float pj  = prec[b*NM+j];
  float wwj = wwb[j];
  float rwv[NR];
  #pragma unroll
  for(int r=0;r<NR;r++) rwv[r]=rw_old[(b*NR+r)*NM+j];
  for(int q=0;q<8;q++){
    float v = (q<4)? pj*rwv[q] : wwj*rwv[q-4];
    float s = waveSum(v);
    if(lane==0) red[wv]=s;
    __syncthreads();
    if(tid==0){ float ss=0; for(int i=0;i<16;i++) ss+=red[i]; scal[q]=ss; }
    __syncthreads();
  }
  const float* mrow = mem + ((size_t)b*NM+j)*NW;
  float dots[NR]={0,0,0,0}; float nrm=0.0f;
  for(int k=0;k<NW;k++){
    float nmv = fmaf(mrow[k], (1.0f - wwj*er[k]), wwj*wvec[k]);
    nrm = fmaf(nmv,nmv,nrm);
    #pragma unroll
    for(int r=0;r<NR;r++) dots[r] = fmaf(nmv, keys[r][k], dots[r]);
  }
  float inv = 1.0f/(sqrtf(nrm)+DELTA);
  float cw[NR];
  for(int r=0;r<NR;r++){
    float logit = scal[12+r]*dots[r]*inv/(scal[8+r]+DELTA);
    float m1 = waveMax(logit); if(lane==0) red[wv]=m1; __syncthreads();
    if(tid==0){ float mm=red[0]; for(int i=1;i<16;i++) mm=fmaxf(mm,red[i]); red[16]=mm; } __syncthreads();
    float e = expf(logit - red[16]);
    float s1 = waveSum(e); if(lane==0) red[wv]=s1; __syncthreads();
    if(tid==0){ float ss=0; for(int i=0;i<16;i++) ss+=red[i]; red[16]=ss; } __syncthreads();
    cw[r] = e/red[16];
    __syncthreads();
  }
  float Ljj = link[((size_t)b<<20) + (size_t)j*(NM+1)];
  #pragma unroll
  for(int r=0;r<NR;r++){
    float F  = RF[(b*NR+r)*NM+j];
    float cc2 = C2[(b*NR+r)*NM+j], cc3 = C3[(b*NR+r)*NM+j];
    float grj = rwv[r];
    float fwd = F - Ljj*grj*(1.0f-2.0f*wwj) + wwj*(scal[r] - pj*grj);
    float bwd = (cc2 - cc3) - Ljj*grj*(1.0f-wwj) - wwj*(cc2 - Ljj*grj) + pj*(scal[4+r] - wwj*grj);
    nrw[r][j] = rm[r][0]*bwd + rm[r][1]*fwd + rm[r][2]*cw[r];
  }
  __syncthreads();
  int w = lane;
  float erw = er[w], wvw = wvec[w];
  float acc[NR]={0,0,0,0};
  int jbase = wv*64;
  for(int jj=0;jj<64;jj++){
    int jr = jbase+jj;
    float wwr = wwb[jr];
    float nmv = fmaf(mem[((size_t)b*NM+jr)*NW + w], (1.0f - wwr*erw), wwr*wvw);
    #pragma unroll
    for(int r=0;r<NR;r++) acc[r] = fmaf(nrw[r][jr], nmv, acc[r]);
  }
  #pragma unroll
  for(int r=0;r<NR;r++) accb[wv][r][w] = acc[r];
  __syncthreads();
  if (tid < 256){
    int r = tid>>6, k = tid&63;
    float s=0;
    for(int v=0;v<16;v++) s += accb[v][r][k];
    out[b*NR*NW + r*NW + k] = s;
  }
}

extern "C" void kernel_launch(void* const* d_in, const int* in_sizes, int n_in,
                              void* d_out, int out_size, void* d_ws, size_t ws_size,
                              hipStream_t stream) {
  (void)in_sizes; (void)n_in; (void)out_size; (void)ws_size;
  const float* xi   = (const float*)d_in[0];
  const float* Wm   = (const float*)d_in[1];
  const float* bW   = (const float*)d_in[2];
  const float* mem  = (const float*)d_in[3];
  const float* link = (const float*)d_in[4];
  const float* prec = (const float*)d_in[5];
  const float* rw   = (const float*)d_in[6];
  const float* wwo  = (const float*)d_in[7];
  const float* uv   = (const float*)d_in[8];
  float* out = (float*)d_out;
  float* ws  = (float*)d_ws;
  float* iface = ws;                 // 64*471 -> pad 30208
  float* wwp   = ws + 30208;         // 65536
  float* RF    = wwp + 65536;        // 262144
  float* C2    = RF + 262144;        // 262144
  float* C3    = C2 + 262144;        // 262144
  hipMemsetAsync(RF, 0, 3*262144*sizeof(float), stream);  // RF,C2,C3
  k_iface<<<NB, 256, 0, stream>>>(xi, Wm, bW, iface);
  k_write<<<NB, 1024, 0, stream>>>(iface, mem, rw, wwo, uv, wwp);
  k_link4<<<dim3(4, 4, NB), 256, 0, stream>>>(link, rw, wwp, RF, C2, C3);
  k_read<<<NB, 1024, 0, stream>>>(iface, mem, link, prec, rw, wwp, RF, C2, C3, out);
}

// Round 7
// 202.180 us; speedup vs baseline: 2.1763x; 1.0899x over previous
//
#include <hip/hip_runtime.h>

#define DELTA 1e-6f

// sizes: b=64, m=1024, w=64, r=4, d=512, iface=471
#define NB 64
#define NM 1024
#define NW 64
#define NR 4
#define ND 512
#define NIF 471

typedef unsigned long long ull;

__device__ __forceinline__ float sigmoidf_(float x){ return 1.0f/(1.0f+expf(-x)); }
__device__ __forceinline__ float softplusf_(float x){ return fmaxf(x,0.0f) + log1pf(expf(-fabsf(x))); }

__device__ __forceinline__ float waveSum(float v){
  #pragma unroll
  for(int o=32;o>0;o>>=1) v += __shfl_down(v,o,64);
  return v;
}
__device__ __forceinline__ float waveMax(float v){
  #pragma unroll
  for(int o=32;o>0;o>>=1) v = fmaxf(v, __shfl_down(v,o,64));
  return v;
}
__device__ __forceinline__ ull shflxor64(ull k, int m){
  unsigned lo = (unsigned)(k & 0xffffffffu), hi = (unsigned)(k>>32);
  lo = (unsigned)__shfl_xor((int)lo, m, 64);
  hi = (unsigned)__shfl_xor((int)hi, m, 64);
  return ((ull)hi<<32)|lo;
}

// ---------------- K1: iface = xi @ W + bW ----------------
__global__ __launch_bounds__(256) void k_iface(const float* __restrict__ xi,
                                               const float* __restrict__ Wm,
                                               const float* __restrict__ bW,
                                               float* __restrict__ iface){
  int b = blockIdx.x;
  __shared__ float xs[ND];
  for(int k=threadIdx.x;k<ND;k+=256) xs[k]=xi[b*ND+k];
  __syncthreads();
  for(int c=threadIdx.x;c<NIF;c+=256){
    float acc = bW[c];
    #pragma unroll 4
    for(int k=0;k<ND;k++) acc = fmaf(xs[k], Wm[k*NIF+c], acc);
    iface[b*NIF+c]=acc;
  }
}

// ---------------- K2: usage/psi, write-content softmax, allocation, new_write_w ----------------
// Sort: bitonic on (u,idx) 64-bit keys; strides<64 in-register via shfl_xor (45 rounds, 0 barriers),
// strides>=64 via ping-pong LDS (10 rounds, 1 barrier each). Cumprod: wave shfl_up scan + 16-partial combine.
__global__ __launch_bounds__(1024) void k_write(
    const float* __restrict__ iface, const float* __restrict__ mem,
    const float* __restrict__ rw_old, const float* __restrict__ ww_old,
    const float* __restrict__ uv, float* __restrict__ wwp){
  int b = blockIdx.x; int tid = threadIdx.x;
  int lane = tid & 63, wv = tid >> 6;
  __shared__ float wkey[NW];
  __shared__ ull skA[NM];
  __shared__ ull skB[NM];
  __shared__ float fb2[NM];
  __shared__ float red[17];
  __shared__ float s_wp[16], s_wp2[16];
  const float* ifb = iface + b*NIF;
  if (tid < NW) wkey[tid] = ifb[260+tid];
  __syncthreads();
  float sw = softplusf_(1.0f + fmaxf(ifb[324],0.0f));
  float ag = sigmoidf_(ifb[457]);
  float wg = sigmoidf_(ifb[458]);
  float fg0=sigmoidf_(ifb[453]), fg1=sigmoidf_(ifb[454]);
  float fg2=sigmoidf_(ifb[455]), fg3=sigmoidf_(ifb[456]);
  float kn=0.0f;
  for(int k=0;k<NW;k++){ float t=wkey[k]; kn += t*t; }
  kn = sqrtf(kn);
  int j = tid;
  float u0  = uv[b*NM+j];
  float wwo = ww_old[b*NM+j];
  float usage = u0 + (1.0f-u0)*(1.0f - (1.0f-wwo));
  float psi = (1.0f - fg0*rw_old[(b*NR+0)*NM+j])
            * (1.0f - fg1*rw_old[(b*NR+1)*NM+j])
            * (1.0f - fg2*rw_old[(b*NR+2)*NM+j])
            * (1.0f - fg3*rw_old[(b*NR+3)*NM+j]);
  usage *= psi;
  float dot=0.0f, nrm=0.0f;
  const float4* mrow4 = (const float4*)(mem + ((size_t)b*NM + j)*NW);
  #pragma unroll 4
  for(int k=0;k<16;k++){
    float4 mv = mrow4[k];
    const float* wk = wkey + k*4;
    dot = fmaf(mv.x,wk[0],dot); dot = fmaf(mv.y,wk[1],dot);
    dot = fmaf(mv.z,wk[2],dot); dot = fmaf(mv.w,wk[3],dot);
    nrm = fmaf(mv.x,mv.x,nrm); nrm = fmaf(mv.y,mv.y,nrm);
    nrm = fmaf(mv.z,mv.z,nrm); nrm = fmaf(mv.w,mv.w,nrm);
  }
  float logit = sw * dot / ((sqrtf(nrm)+DELTA)*(kn+DELTA));
  float m1 = waveMax(logit); if(lane==0) red[wv]=m1; __syncthreads();
  if(tid==0){ float mm=red[0]; for(int i=1;i<16;i++) mm=fmaxf(mm,red[i]); red[16]=mm; } __syncthreads();
  float e = expf(logit - red[16]);
  float s1 = waveSum(e); if(lane==0) red[wv]=s1; __syncthreads();
  if(tid==0){ float ss=0; for(int i=0;i<16;i++) ss+=red[i]; red[16]=ss; } __syncthreads();
  float wcw = e/red[16];
  // ---- bitonic sort of (u, idx) ----
  float u = DELTA + (1.0f-DELTA)*usage;
  ull k = ((ull)__float_as_uint(u) << 32) | (unsigned)tid;
  bool useA = true;
  for (int k2=2; k2<=NM; k2<<=1){
    for (int jj=k2>>1; jj>0; jj>>=1){
      ull p;
      if (jj >= 64){
        ull* buf = useA ? skA : skB;
        buf[tid] = k;
        __syncthreads();
        p = buf[tid^jj];
        useA = !useA;
      } else {
        p = shflxor64(k, jj);
      }
      bool lower = (tid & jj) == 0;
      bool asc   = (tid & k2) == 0;
      bool takeMin = (lower == asc);
      k = takeMin ? (k<p ? k : p) : (k>p ? k : p);
    }
  }
  float su = __uint_as_float((unsigned)(k>>32));
  int phi  = (int)(k & 0xffffffffu);
  // ---- inclusive cumprod over sorted order: wave scan + cross-wave prefix ----
  float sc = su;
  #pragma unroll
  for (int off=1; off<64; off<<=1){
    float t = __shfl_up(sc, off, 64);
    if (lane >= off) sc *= t;
  }
  if (lane==63) s_wp[wv] = sc;
  __syncthreads();
  if (tid==0){
    float p=1.0f;
    for (int w=0;w<16;w++){ float t=s_wp[w]; s_wp2[w]=p; p*=t; }
  }
  __syncthreads();
  float P = sc * s_wp2[wv];
  float salloc = (1.0f - su)*P;
  fb2[phi] = salloc;
  __syncthreads();
  float alloc = fb2[tid];
  wwp[b*NM+tid] = wg*(ag*alloc + (1.0f-ag)*wcw);
}

// ---------------- K3: one streaming pass over L (LDS-staged, reduction-free) ----------------
// Block tile 256x256, 8 chunks of 32 rows staged in LDS (40.5KB total -> 4 blocks/CU).
// RF[r,j] = sum_n L[j,n]*g[r,n]*(1-ww[j]-ww[n])  (phase R: 2 lanes/row, shfl_xor(32) combine)
// C2[r,n] = sum_m L[m,n]*g[r,m];  C3 with *ww[m]   (phase C: lane owns 4 cols)
// XOR-swizzle (16B blk ^ row&7) keeps both row-wise and col-wise b128 reads conflict-free.
// Live set ~60 VGPR -> spill-proof (rounds 3-5 lesson: big live sets get spilled at default budgets).
__global__ __launch_bounds__(256) void k_link5(
    const float* __restrict__ link, const float* __restrict__ rw,
    const float* __restrict__ wwp,
    float* __restrict__ RF, float* __restrict__ C2, float* __restrict__ C3){
  int cx = blockIdx.x, ry = blockIdx.y, b = blockIdx.z;
  int tid = threadIdx.x, lane = tid&63, wv = tid>>6;
  __shared__ float4 s_L4[32*64];   // 32KB
  __shared__ float4 s_gcol4[256];  // 4KB {g0..g3} per col
  __shared__ float  s_mwc[256];    // 1KB: 1-ww[col]
  __shared__ float4 s_grow4[32];   // per-row {g0..g3}
  __shared__ float  s_wwr[32];     // ww[row]
  __shared__ float4 s_rfp4[128];   // 2KB phase-R partials [wave][row]
  const float* Lb = link + ((size_t)b<<20);
  int colbase = cx*256, rowbase = ry*256;
  {
    float g0 = rw[(b*NR+0)*NM + colbase + tid];
    float g1 = rw[(b*NR+1)*NM + colbase + tid];
    float g2 = rw[(b*NR+2)*NM + colbase + tid];
    float g3 = rw[(b*NR+3)*NM + colbase + tid];
    s_gcol4[tid] = make_float4(g0,g1,g2,g3);
    s_mwc[tid] = 1.0f - wwp[b*NM + colbase + tid];
  }
  float c2a[NR][4], c3a[NR][4];
  #pragma unroll
  for(int r=0;r<NR;r++){
    #pragma unroll
    for(int e=0;e<4;e++){ c2a[r][e]=0.0f; c3a[r][e]=0.0f; }
  }
  for (int ch=0; ch<8; ++ch){
    int rb = rowbase + ch*32;
    if (tid < 128) ((float*)s_grow4)[tid] = rw[(b*NR+(tid&3))*NM + rb + (tid>>2)];
    if (tid < 32)  s_wwr[tid] = wwp[b*NM + rb + tid];
    #pragma unroll
    for (int jq=0;jq<8;jq++){
      int rl = wv + 4*jq;
      float4 lv = *(const float4*)(Lb + (size_t)(rb+rl)*NM + colbase + lane*4);
      s_L4[rl*64 + (lane ^ (rl&7))] = lv;
    }
    __syncthreads();
    // ---- phase R: row = lane&31, half h = lane>>5; wave covers 64 cols ----
    {
      int row = lane&31, h = lane>>5, row7 = row&7;
      float wwj = s_wwr[row];
      float rf[4] = {0,0,0,0};
      #pragma unroll 2
      for (int i=0;i<8;i++){
        int cb = wv*16 + h*8 + i;
        float4 lv = s_L4[row*64 + (cb ^ row7)];
        float4 mw = ((const float4*)s_mwc)[cb];
        float le[4] = {lv.x,lv.y,lv.z,lv.w};
        float mv[4] = {mw.x,mw.y,mw.z,mw.w};
        #pragma unroll
        for (int e=0;e<4;e++){
          float4 gv = s_gcol4[cb*4+e];
          float ls = le[e]*(mv[e]-wwj);
          rf[0] = fmaf(ls, gv.x, rf[0]);
          rf[1] = fmaf(ls, gv.y, rf[1]);
          rf[2] = fmaf(ls, gv.z, rf[2]);
          rf[3] = fmaf(ls, gv.w, rf[3]);
        }
      }
      #pragma unroll
      for (int r=0;r<NR;r++) rf[r] += __shfl_xor(rf[r], 32, 64);
      if (lane < 32) s_rfp4[wv*32+row] = make_float4(rf[0],rf[1],rf[2],rf[3]);
    }
    // ---- phase C: wave covers 8 rows, lane owns 4 cols ----
    #pragma unroll 2
    for (int ri=0; ri<8; ri++){
      int row = wv*8 + ri;
      float4 lv = s_L4[row*64 + (lane ^ (row&7))];
      float4 gg = s_grow4[row];
      float wwr = s_wwr[row];
      float le[4] = {lv.x,lv.y,lv.z,lv.w};
      float ggv[4] = {gg.x,gg.y,gg.z,gg.w};
      float ggw[4];
      #pragma unroll
      for (int r=0;r<NR;r++) ggw[r] = ggv[r]*wwr;
      #pragma unroll
      for (int e=0;e<4;e++){
        #pragma unroll
        for (int r=0;r<NR;r++){
          c2a[r][e] = fmaf(le[e], ggv[r], c2a[r][e]);
          c3a[r][e] = fmaf(le[e], ggw[r], c3a[r][e]);
        }
      }
    }
    __syncthreads();
    if (tid < 128){
      int row = tid>>2, r = tid&3;
      float s = ((const float*)&s_rfp4[0*32+row])[r] + ((const float*)&s_rfp4[1*32+row])[r]
              + ((const float*)&s_rfp4[2*32+row])[r] + ((const float*)&s_rfp4[3*32+row])[r];
      atomicAdd(&RF[(b*NR+r)*NM + rb + row], s);
    }
  }
  // ---- c2/c3 cross-wave combine (reuse s_L4), then atomic flush ----
  __syncthreads();
  float4* s_comb = s_L4;
  #pragma unroll
  for (int r=0;r<NR;r++){
    s_comb[(wv*64+lane)*8 + r]     = make_float4(c2a[r][0],c2a[r][1],c2a[r][2],c2a[r][3]);
    s_comb[(wv*64+lane)*8 + 4 + r] = make_float4(c3a[r][0],c3a[r][1],c3a[r][2],c3a[r][3]);
  }
  __syncthreads();
  for (int t=tid; t<512; t+=256){
    int lc = t>>3, q = t&7;
    float4 a = s_comb[(0*64+lc)*8+q];
    float4 bb= s_comb[(1*64+lc)*8+q];
    float4 c = s_comb[(2*64+lc)*8+q];
    float4 d = s_comb[(3*64+lc)*8+q];
    float sx=a.x+bb.x+c.x+d.x, sy=a.y+bb.y+c.y+d.y, sz=a.z+bb.z+c.z+d.z, sw=a.w+bb.w+c.w+d.w;
    float* dst = (q<4) ? &C2[(b*NR+q)*NM + colbase + lc*4]
                       : &C3[(b*NR+(q-4))*NM + colbase + lc*4];
    atomicAdd(dst+0, sx); atomicAdd(dst+1, sy); atomicAdd(dst+2, sz); atomicAdd(dst+3, sw);
  }
}

// ---------------- K4: read-content softmax, forward/backward finalize, read_vectors ----------------
__global__ __launch_bounds__(1024) void k_read(
    const float* __restrict__ iface, const float* __restrict__ mem,
    const float* __restrict__ link, const float* __restrict__ prec,
    const float* __restrict__ rw_old, const float* __restrict__ wwp,
    const float* __restrict__ RF,
    const float* __restrict__ C2, const float* __restrict__ C3,
    float* __restrict__ out){
  int b = blockIdx.x; int tid = threadIdx.x; int lane=tid&63, wv=tid>>6;
  __shared__ float keys[NR][NW];
  __shared__ float er[NW], wvec[NW];
  __shared__ float wwb[NM];
  __shared__ float nrw[NR][NM];
  __shared__ float s_pk[16][8];
  __shared__ float scal[16];   // [0..3]=Pr, [4..7]=Kr, [8..11]=keynorm, [12..15]=strength
  __shared__ float smax[NR], ssum[NR];
  __shared__ float rm[NR][3];
  __shared__ float accb[16][NR][NW];
  const float* ifb = iface + b*NIF;
  if (tid < 256){ int r=tid>>6, kk=tid&63; keys[r][kk] = ifb[r*NW+kk]; }
  if (tid >= 256 && tid < 320){ int kk=tid-256; er[kk]=sigmoidf_(ifb[325+kk]); wvec[kk]=ifb[389+kk]; }
  wwb[tid] = wwp[b*NM+tid];
  if (tid == 0){
    for(int mo=0;mo<3;mo++){
      float x0=ifb[458+0*3+mo], x1=ifb[458+1*3+mo], x2=ifb[458+2*3+mo], x3=ifb[458+3*3+mo];
      float mx = fmaxf(fmaxf(x0,x1),fmaxf(x2,x3));
      float e0=expf(x0-mx),e1=expf(x1-mx),e2=expf(x2-mx),e3=expf(x3-mx);
      float s=e0+e1+e2+e3;
      rm[0][mo]=e0/s; rm[1][mo]=e1/s; rm[2][mo]=e2/s; rm[3][mo]=e3/s;
    }
  }
  if (tid >= 320 && tid < 324){
    int r = tid-320;
    float knv=0;
    for(int k=0;k<NW;k++){ float t=ifb[r*NW+k]; knv += t*t; }
    scal[8+r]  = sqrtf(knv);
    scal[12+r] = softplusf_(1.0f + fmaxf(ifb[256+r],0.0f));
  }
  __syncthreads();
  int j = tid;
  float pj  = prec[b*NM+j];
  float wwj = wwb[j];
  float rwv[NR];
  #pragma unroll
  for(int r=0;r<NR;r++) rwv[r]=rw_old[(b*NR+r)*NM+j];
  // Pr[r]=sum prec*rw, Kr[r]=sum ww*rw : batched 8 waveSums + 2 barriers
  {
    float v8[8];
    #pragma unroll
    for(int r=0;r<NR;r++){ v8[r] = pj*rwv[r]; v8[4+r] = wwj*rwv[r]; }
    #pragma unroll
    for(int q=0;q<8;q++){
      float s = waveSum(v8[q]);
      if(lane==0) s_pk[wv][q]=s;
    }
    __syncthreads();
    if (tid < 8){
      float ss=0;
      for(int w=0;w<16;w++) ss += s_pk[w][tid];
      scal[tid]=ss;
    }
    __syncthreads();
  }
  // content logits on new_memory rows (computed on the fly)
  const float* mrow = mem + ((size_t)b*NM+j)*NW;
  float dots[NR]={0,0,0,0}; float nrm=0.0f;
  for(int k=0;k<NW;k++){
    float nmv = fmaf(mrow[k], (1.0f - wwj*er[k]), wwj*wvec[k]);
    nrm = fmaf(nmv,nmv,nrm);
    #pragma unroll
    for(int r=0;r<NR;r++) dots[r] = fmaf(nmv, keys[r][k], dots[r]);
  }
  float inv = 1.0f/(sqrtf(nrm)+DELTA);
  // batched 4-row softmax over m: 4 barriers
  float logit[NR], ce[NR], cw[NR];
  #pragma unroll
  for(int r=0;r<NR;r++) logit[r] = scal[12+r]*dots[r]*inv/(scal[8+r]+DELTA);
  #pragma unroll
  for(int r=0;r<NR;r++){
    float m1 = waveMax(logit[r]);
    if(lane==0) s_pk[wv][r]=m1;
  }
  __syncthreads();
  if (tid < NR){
    float mm=s_pk[0][tid];
    for(int w=1;w<16;w++) mm=fmaxf(mm,s_pk[w][tid]);
    smax[tid]=mm;
  }
  __syncthreads();
  #pragma unroll
  for(int r=0;r<NR;r++){
    ce[r] = expf(logit[r]-smax[r]);
    float s1 = waveSum(ce[r]);
    if(lane==0) s_pk[wv][r]=s1;
  }
  __syncthreads();
  if (tid < NR){
    float ss=0;
    for(int w=0;w<16;w++) ss += s_pk[w][tid];
    ssum[tid]=ss;
  }
  __syncthreads();
  #pragma unroll
  for(int r=0;r<NR;r++) cw[r] = ce[r]/ssum[r];
  // forward/backward finalize
  float Ljj = link[((size_t)b<<20) + (size_t)j*(NM+1)];
  #pragma unroll
  for(int r=0;r<NR;r++){
    float F  = RF[(b*NR+r)*NM+j];
    float cc2 = C2[(b*NR+r)*NM+j], cc3 = C3[(b*NR+r)*NM+j];
    float grj = rwv[r];
    float fwd = F - Ljj*grj*(1.0f-2.0f*wwj) + wwj*(scal[r] - pj*grj);
    float bwd = (cc2 - cc3) - Ljj*grj*(1.0f-wwj) - wwj*(cc2 - Ljj*grj) + pj*(scal[4+r] - wwj*grj);
    nrw[r][j] = rm[r][0]*bwd + rm[r][1]*fwd + rm[r][2]*cw[r];
  }
  __syncthreads();
  // read_vectors
  int w = lane;
  float erw = er[w], wvw = wvec[w];
  float acc[NR]={0,0,0,0};
  int jbase = wv*64;
  for(int jj=0;jj<64;jj++){
    int jr = jbase+jj;
    float wwr = wwb[jr];
    float nmv = fmaf(mem[((size_t)b*NM+jr)*NW + w], (1.0f - wwr*erw), wwr*wvw);
    #pragma unroll
    for(int r=0;r<NR;r++) acc[r] = fmaf(nrw[r][jr], nmv, acc[r]);
  }
  #pragma unroll
  for(int r=0;r<NR;r++) accb[wv][r][w] = acc[r];
  __syncthreads();
  if (tid < 256){
    int r = tid>>6, kk = tid&63;
    float s=0;
    for(int v=0;v<16;v++) s += accb[v][r][kk];
    out[b*NR*NW + r*NW + kk] = s;
  }
}

extern "C" void kernel_launch(void* const* d_in, const int* in_sizes, int n_in,
                              void* d_out, int out_size, void* d_ws, size_t ws_size,
                              hipStream_t stream) {
  (void)in_sizes; (void)n_in; (void)out_size; (void)ws_size;
  const float* xi   = (const float*)d_in[0];
  const float* Wm   = (const float*)d_in[1];
  const float* bW   = (const float*)d_in[2];
  const float* mem  = (const float*)d_in[3];
  const float* link = (const float*)d_in[4];
  const float* prec = (const float*)d_in[5];
  const float* rw   = (const float*)d_in[6];
  const float* wwo  = (const float*)d_in[7];
  const float* uv   = (const float*)d_in[8];
  float* out = (float*)d_out;
  float* ws  = (float*)d_ws;
  float* iface = ws;                 // 64*471 -> pad 30208
  float* wwp   = ws + 30208;         // 65536
  float* RF    = wwp + 65536;        // 262144
  float* C2    = RF + 262144;        // 262144
  float* C3    = C2 + 262144;        // 262144
  hipMemsetAsync(RF, 0, 3*262144*sizeof(float), stream);  // RF,C2,C3
  k_iface<<<NB, 256, 0, stream>>>(xi, Wm, bW, iface);
  k_write<<<NB, 1024, 0, stream>>>(iface, mem, rw, wwo, uv, wwp);
  k_link5<<<dim3(4, 4, NB), 256, 0, stream>>>(link, rw, wwp, RF, C2, C3);
  k_read<<<NB, 1024, 0, stream>>>(iface, mem, link, prec, rw, wwp, RF, C2, C3, out);
}

// Round 8
// 201.303 us; speedup vs baseline: 2.1857x; 1.0044x over previous
//
#include <hip/hip_runtime.h>

#define DELTA 1e-6f

// sizes: b=64, m=1024, w=64, r=4, d=512, iface=471
#define NB 64
#define NM 1024
#define NW 64
#define NR 4
#define ND 512
#define NIF 471

typedef unsigned long long ull;

__device__ __forceinline__ float sigmoidf_(float x){ return 1.0f/(1.0f+expf(-x)); }
__device__ __forceinline__ float softplusf_(float x){ return fmaxf(x,0.0f) + log1pf(expf(-fabsf(x))); }

__device__ __forceinline__ float waveSum(float v){
  #pragma unroll
  for(int o=32;o>0;o>>=1) v += __shfl_down(v,o,64);
  return v;
}
__device__ __forceinline__ float waveMax(float v){
  #pragma unroll
  for(int o=32;o>0;o>>=1) v = fmaxf(v, __shfl_down(v,o,64));
  return v;
}
__device__ __forceinline__ ull shflxor64(ull k, int m){
  unsigned lo = (unsigned)(k & 0xffffffffu), hi = (unsigned)(k>>32);
  lo = (unsigned)__shfl_xor((int)lo, m, 64);
  hi = (unsigned)__shfl_xor((int)hi, m, 64);
  return ((ull)hi<<32)|lo;
}

// ---------------- K0: zero RF/C2/C3 (hipMemsetAsync's fillBufferAligned runs at
// ~20 GB/s with a tiny grid -> 157us for 3MB, was 75% of total. This: ~1-2us.) ----------------
__global__ __launch_bounds__(256) void k_zero(float4* __restrict__ p, int n4){
  int i = blockIdx.x*256 + threadIdx.x;
  if (i < n4) p[i] = make_float4(0.f,0.f,0.f,0.f);
}

// ---------------- K1: iface = xi @ W + bW ----------------
__global__ __launch_bounds__(256) void k_iface(const float* __restrict__ xi,
                                               const float* __restrict__ Wm,
                                               const float* __restrict__ bW,
                                               float* __restrict__ iface){
  int b = blockIdx.x;
  __shared__ float xs[ND];
  for(int k=threadIdx.x;k<ND;k+=256) xs[k]=xi[b*ND+k];
  __syncthreads();
  for(int c=threadIdx.x;c<NIF;c+=256){
    float acc = bW[c];
    #pragma unroll 4
    for(int k=0;k<ND;k++) acc = fmaf(xs[k], Wm[k*NIF+c], acc);
    iface[b*NIF+c]=acc;
  }
}

// ---------------- K2: usage/psi, write-content softmax, allocation, new_write_w ----------------
// Sort: bitonic on (u,idx) 64-bit keys; strides<64 in-register via shfl_xor (45 rounds, 0 barriers),
// strides>=64 via ping-pong LDS (10 rounds, 1 barrier each). Cumprod: wave shfl_up scan + 16-partial combine.
__global__ __launch_bounds__(1024) void k_write(
    const float* __restrict__ iface, const float* __restrict__ mem,
    const float* __restrict__ rw_old, const float* __restrict__ ww_old,
    const float* __restrict__ uv, float* __restrict__ wwp){
  int b = blockIdx.x; int tid = threadIdx.x;
  int lane = tid & 63, wv = tid >> 6;
  __shared__ float wkey[NW];
  __shared__ ull skA[NM];
  __shared__ ull skB[NM];
  __shared__ float fb2[NM];
  __shared__ float red[17];
  __shared__ float s_wp[16], s_wp2[16];
  const float* ifb = iface + b*NIF;
  if (tid < NW) wkey[tid] = ifb[260+tid];
  __syncthreads();
  float sw = softplusf_(1.0f + fmaxf(ifb[324],0.0f));
  float ag = sigmoidf_(ifb[457]);
  float wg = sigmoidf_(ifb[458]);
  float fg0=sigmoidf_(ifb[453]), fg1=sigmoidf_(ifb[454]);
  float fg2=sigmoidf_(ifb[455]), fg3=sigmoidf_(ifb[456]);
  float kn=0.0f;
  for(int k=0;k<NW;k++){ float t=wkey[k]; kn += t*t; }
  kn = sqrtf(kn);
  int j = tid;
  float u0  = uv[b*NM+j];
  float wwo = ww_old[b*NM+j];
  float usage = u0 + (1.0f-u0)*(1.0f - (1.0f-wwo));
  float psi = (1.0f - fg0*rw_old[(b*NR+0)*NM+j])
            * (1.0f - fg1*rw_old[(b*NR+1)*NM+j])
            * (1.0f - fg2*rw_old[(b*NR+2)*NM+j])
            * (1.0f - fg3*rw_old[(b*NR+3)*NM+j]);
  usage *= psi;
  float dot=0.0f, nrm=0.0f;
  const float4* mrow4 = (const float4*)(mem + ((size_t)b*NM + j)*NW);
  #pragma unroll 4
  for(int k=0;k<16;k++){
    float4 mv = mrow4[k];
    const float* wk = wkey + k*4;
    dot = fmaf(mv.x,wk[0],dot); dot = fmaf(mv.y,wk[1],dot);
    dot = fmaf(mv.z,wk[2],dot); dot = fmaf(mv.w,wk[3],dot);
    nrm = fmaf(mv.x,mv.x,nrm); nrm = fmaf(mv.y,mv.y,nrm);
    nrm = fmaf(mv.z,mv.z,nrm); nrm = fmaf(mv.w,mv.w,nrm);
  }
  float logit = sw * dot / ((sqrtf(nrm)+DELTA)*(kn+DELTA));
  float m1 = waveMax(logit); if(lane==0) red[wv]=m1; __syncthreads();
  if(tid==0){ float mm=red[0]; for(int i=1;i<16;i++) mm=fmaxf(mm,red[i]); red[16]=mm; } __syncthreads();
  float e = expf(logit - red[16]);
  float s1 = waveSum(e); if(lane==0) red[wv]=s1; __syncthreads();
  if(tid==0){ float ss=0; for(int i=0;i<16;i++) ss+=red[i]; red[16]=ss; } __syncthreads();
  float wcw = e/red[16];
  // ---- bitonic sort of (u, idx) ----
  float u = DELTA + (1.0f-DELTA)*usage;
  ull k = ((ull)__float_as_uint(u) << 32) | (unsigned)tid;
  bool useA = true;
  for (int k2=2; k2<=NM; k2<<=1){
    for (int jj=k2>>1; jj>0; jj>>=1){
      ull p;
      if (jj >= 64){
        ull* buf = useA ? skA : skB;
        buf[tid] = k;
        __syncthreads();
        p = buf[tid^jj];
        useA = !useA;
      } else {
        p = shflxor64(k, jj);
      }
      bool lower = (tid & jj) == 0;
      bool asc   = (tid & k2) == 0;
      bool takeMin = (lower == asc);
      k = takeMin ? (k<p ? k : p) : (k>p ? k : p);
    }
  }
  float su = __uint_as_float((unsigned)(k>>32));
  int phi  = (int)(k & 0xffffffffu);
  // ---- inclusive cumprod over sorted order: wave scan + cross-wave prefix ----
  float sc = su;
  #pragma unroll
  for (int off=1; off<64; off<<=1){
    float t = __shfl_up(sc, off, 64);
    if (lane >= off) sc *= t;
  }
  if (lane==63) s_wp[wv] = sc;
  __syncthreads();
  if (tid==0){
    float p=1.0f;
    for (int w=0;w<16;w++){ float t=s_wp[w]; s_wp2[w]=p; p*=t; }
  }
  __syncthreads();
  float P = sc * s_wp2[wv];
  float salloc = (1.0f - su)*P;
  fb2[phi] = salloc;
  __syncthreads();
  float alloc = fb2[tid];
  wwp[b*NM+tid] = wg*(ag*alloc + (1.0f-ag)*wcw);
}

// ---------------- K3: one streaming pass over L (LDS-staged, reduction-free) ----------------
// Block tile 256x256, 8 chunks of 32 rows staged in LDS (40.5KB total -> 4 blocks/CU).
// RF[r,j] = sum_n L[j,n]*g[r,n]*(1-ww[j]-ww[n])  (phase R: 2 lanes/row, shfl_xor(32) combine)
// C2[r,n] = sum_m L[m,n]*g[r,m];  C3 with *ww[m]   (phase C: lane owns 4 cols)
// XOR-swizzle (16B blk ^ row&7) keeps both row-wise and col-wise b128 reads conflict-free.
// Live set ~60 VGPR -> spill-proof (rounds 3-5 lesson: big live sets get spilled at default budgets).
__global__ __launch_bounds__(256) void k_link5(
    const float* __restrict__ link, const float* __restrict__ rw,
    const float* __restrict__ wwp,
    float* __restrict__ RF, float* __restrict__ C2, float* __restrict__ C3){
  int cx = blockIdx.x, ry = blockIdx.y, b = blockIdx.z;
  int tid = threadIdx.x, lane = tid&63, wv = tid>>6;
  __shared__ float4 s_L4[32*64];   // 32KB
  __shared__ float4 s_gcol4[256];  // 4KB {g0..g3} per col
  __shared__ float  s_mwc[256];    // 1KB: 1-ww[col]
  __shared__ float4 s_grow4[32];   // per-row {g0..g3}
  __shared__ float  s_wwr[32];     // ww[row]
  __shared__ float4 s_rfp4[128];   // 2KB phase-R partials [wave][row]
  const float* Lb = link + ((size_t)b<<20);
  int colbase = cx*256, rowbase = ry*256;
  {
    float g0 = rw[(b*NR+0)*NM + colbase + tid];
    float g1 = rw[(b*NR+1)*NM + colbase + tid];
    float g2 = rw[(b*NR+2)*NM + colbase + tid];
    float g3 = rw[(b*NR+3)*NM + colbase + tid];
    s_gcol4[tid] = make_float4(g0,g1,g2,g3);
    s_mwc[tid] = 1.0f - wwp[b*NM + colbase + tid];
  }
  float c2a[NR][4], c3a[NR][4];
  #pragma unroll
  for(int r=0;r<NR;r++){
    #pragma unroll
    for(int e=0;e<4;e++){ c2a[r][e]=0.0f; c3a[r][e]=0.0f; }
  }
  for (int ch=0; ch<8; ++ch){
    int rb = rowbase + ch*32;
    if (tid < 128) ((float*)s_grow4)[tid] = rw[(b*NR+(tid&3))*NM + rb + (tid>>2)];
    if (tid < 32)  s_wwr[tid] = wwp[b*NM + rb + tid];
    #pragma unroll
    for (int jq=0;jq<8;jq++){
      int rl = wv + 4*jq;
      float4 lv = *(const float4*)(Lb + (size_t)(rb+rl)*NM + colbase + lane*4);
      s_L4[rl*64 + (lane ^ (rl&7))] = lv;
    }
    __syncthreads();
    // ---- phase R: row = lane&31, half h = lane>>5; wave covers 64 cols ----
    {
      int row = lane&31, h = lane>>5, row7 = row&7;
      float wwj = s_wwr[row];
      float rf[4] = {0,0,0,0};
      #pragma unroll 2
      for (int i=0;i<8;i++){
        int cb = wv*16 + h*8 + i;
        float4 lv = s_L4[row*64 + (cb ^ row7)];
        float4 mw = ((const float4*)s_mwc)[cb];
        float le[4] = {lv.x,lv.y,lv.z,lv.w};
        float mv[4] = {mw.x,mw.y,mw.z,mw.w};
        #pragma unroll
        for (int e=0;e<4;e++){
          float4 gv = s_gcol4[cb*4+e];
          float ls = le[e]*(mv[e]-wwj);
          rf[0] = fmaf(ls, gv.x, rf[0]);
          rf[1] = fmaf(ls, gv.y, rf[1]);
          rf[2] = fmaf(ls, gv.z, rf[2]);
          rf[3] = fmaf(ls, gv.w, rf[3]);
        }
      }
      #pragma unroll
      for (int r=0;r<NR;r++) rf[r] += __shfl_xor(rf[r], 32, 64);
      if (lane < 32) s_rfp4[wv*32+row] = make_float4(rf[0],rf[1],rf[2],rf[3]);
    }
    // ---- phase C: wave covers 8 rows, lane owns 4 cols ----
    #pragma unroll 2
    for (int ri=0; ri<8; ri++){
      int row = wv*8 + ri;
      float4 lv = s_L4[row*64 + (lane ^ (row&7))];
      float4 gg = s_grow4[row];
      float wwr = s_wwr[row];
      float le[4] = {lv.x,lv.y,lv.z,lv.w};
      float ggv[4] = {gg.x,gg.y,gg.z,gg.w};
      float ggw[4];
      #pragma unroll
      for (int r=0;r<NR;r++) ggw[r] = ggv[r]*wwr;
      #pragma unroll
      for (int e=0;e<4;e++){
        #pragma unroll
        for (int r=0;r<NR;r++){
          c2a[r][e] = fmaf(le[e], ggv[r], c2a[r][e]);
          c3a[r][e] = fmaf(le[e], ggw[r], c3a[r][e]);
        }
      }
    }
    __syncthreads();
    if (tid < 128){
      int row = tid>>2, r = tid&3;
      float s = ((const float*)&s_rfp4[0*32+row])[r] + ((const float*)&s_rfp4[1*32+row])[r]
              + ((const float*)&s_rfp4[2*32+row])[r] + ((const float*)&s_rfp4[3*32+row])[r];
      atomicAdd(&RF[(b*NR+r)*NM + rb + row], s);
    }
  }
  // ---- c2/c3 cross-wave combine (reuse s_L4), then atomic flush ----
  __syncthreads();
  float4* s_comb = s_L4;
  #pragma unroll
  for (int r=0;r<NR;r++){
    s_comb[(wv*64+lane)*8 + r]     = make_float4(c2a[r][0],c2a[r][1],c2a[r][2],c2a[r][3]);
    s_comb[(wv*64+lane)*8 + 4 + r] = make_float4(c3a[r][0],c3a[r][1],c3a[r][2],c3a[r][3]);
  }
  __syncthreads();
  for (int t=tid; t<512; t+=256){
    int lc = t>>3, q = t&7;
    float4 a = s_comb[(0*64+lc)*8+q];
    float4 bb= s_comb[(1*64+lc)*8+q];
    float4 c = s_comb[(2*64+lc)*8+q];
    float4 d = s_comb[(3*64+lc)*8+q];
    float sx=a.x+bb.x+c.x+d.x, sy=a.y+bb.y+c.y+d.y, sz=a.z+bb.z+c.z+d.z, sw=a.w+bb.w+c.w+d.w;
    float* dst = (q<4) ? &C2[(b*NR+q)*NM + colbase + lc*4]
                       : &C3[(b*NR+(q-4))*NM + colbase + lc*4];
    atomicAdd(dst+0, sx); atomicAdd(dst+1, sy); atomicAdd(dst+2, sz); atomicAdd(dst+3, sw);
  }
}

// ---------------- K4: read-content softmax, forward/backward finalize, read_vectors ----------------
__global__ __launch_bounds__(1024) void k_read(
    const float* __restrict__ iface, const float* __restrict__ mem,
    const float* __restrict__ link, const float* __restrict__ prec,
    const float* __restrict__ rw_old, const float* __restrict__ wwp,
    const float* __restrict__ RF,
    const float* __restrict__ C2, const float* __restrict__ C3,
    float* __restrict__ out){
  int b = blockIdx.x; int tid = threadIdx.x; int lane=tid&63, wv=tid>>6;
  __shared__ float keys[NR][NW];
  __shared__ float er[NW], wvec[NW];
  __shared__ float wwb[NM];
  __shared__ float nrw[NR][NM];
  __shared__ float s_pk[16][8];
  __shared__ float scal[16];   // [0..3]=Pr, [4..7]=Kr, [8..11]=keynorm, [12..15]=strength
  __shared__ float smax[NR], ssum[NR];
  __shared__ float rm[NR][3];
  __shared__ float accb[16][NR][NW];
  const float* ifb = iface + b*NIF;
  if (tid < 256){ int r=tid>>6, kk=tid&63; keys[r][kk] = ifb[r*NW+kk]; }
  if (tid >= 256 && tid < 320){ int kk=tid-256; er[kk]=sigmoidf_(ifb[325+kk]); wvec[kk]=ifb[389+kk]; }
  wwb[tid] = wwp[b*NM+tid];
  if (tid == 0){
    for(int mo=0;mo<3;mo++){
      float x0=ifb[458+0*3+mo], x1=ifb[458+1*3+mo], x2=ifb[458+2*3+mo], x3=ifb[458+3*3+mo];
      float mx = fmaxf(fmaxf(x0,x1),fmaxf(x2,x3));
      float e0=expf(x0-mx),e1=expf(x1-mx),e2=expf(x2-mx),e3=expf(x3-mx);
      float s=e0+e1+e2+e3;
      rm[0][mo]=e0/s; rm[1][mo]=e1/s; rm[2][mo]=e2/s; rm[3][mo]=e3/s;
    }
  }
  if (tid >= 320 && tid < 324){
    int r = tid-320;
    float knv=0;
    for(int k=0;k<NW;k++){ float t=ifb[r*NW+k]; knv += t*t; }
    scal[8+r]  = sqrtf(knv);
    scal[12+r] = softplusf_(1.0f + fmaxf(ifb[256+r],0.0f));
  }
  __syncthreads();
  int j = tid;
  float pj  = prec[b*NM+j];
  float wwj = wwb[j];
  float rwv[NR];
  #pragma unroll
  for(int r=0;r<NR;r++) rwv[r]=rw_old[(b*NR+r)*NM+j];
  // Pr[r]=sum prec*rw, Kr[r]=sum ww*rw : batched 8 waveSums + 2 barriers
  {
    float v8[8];
    #pragma unroll
    for(int r=0;r<NR;r++){ v8[r] = pj*rwv[r]; v8[4+r] = wwj*rwv[r]; }
    #pragma unroll
    for(int q=0;q<8;q++){
      float s = waveSum(v8[q]);
      if(lane==0) s_pk[wv][q]=s;
    }
    __syncthreads();
    if (tid < 8){
      float ss=0;
      for(int w=0;w<16;w++) ss += s_pk[w][tid];
      scal[tid]=ss;
    }
    __syncthreads();
  }
  // content logits on new_memory rows (computed on the fly)
  const float* mrow = mem + ((size_t)b*NM+j)*NW;
  float dots[NR]={0,0,0,0}; float nrm=0.0f;
  for(int k=0;k<NW;k++){
    float nmv = fmaf(mrow[k], (1.0f - wwj*er[k]), wwj*wvec[k]);
    nrm = fmaf(nmv,nmv,nrm);
    #pragma unroll
    for(int r=0;r<NR;r++) dots[r] = fmaf(nmv, keys[r][k], dots[r]);
  }
  float inv = 1.0f/(sqrtf(nrm)+DELTA);
  // batched 4-row softmax over m: 4 barriers
  float logit[NR], ce[NR], cw[NR];
  #pragma unroll
  for(int r=0;r<NR;r++) logit[r] = scal[12+r]*dots[r]*inv/(scal[8+r]+DELTA);
  #pragma unroll
  for(int r=0;r<NR;r++){
    float m1 = waveMax(logit[r]);
    if(lane==0) s_pk[wv][r]=m1;
  }
  __syncthreads();
  if (tid < NR){
    float mm=s_pk[0][tid];
    for(int w=1;w<16;w++) mm=fmaxf(mm,s_pk[w][tid]);
    smax[tid]=mm;
  }
  __syncthreads();
  #pragma unroll
  for(int r=0;r<NR;r++){
    ce[r] = expf(logit[r]-smax[r]);
    float s1 = waveSum(ce[r]);
    if(lane==0) s_pk[wv][r]=s1;
  }
  __syncthreads();
  if (tid < NR){
    float ss=0;
    for(int w=0;w<16;w++) ss += s_pk[w][tid];
    ssum[tid]=ss;
  }
  __syncthreads();
  #pragma unroll
  for(int r=0;r<NR;r++) cw[r] = ce[r]/ssum[r];
  // forward/backward finalize
  float Ljj = link[((size_t)b<<20) + (size_t)j*(NM+1)];
  #pragma unroll
  for(int r=0;r<NR;r++){
    float F  = RF[(b*NR+r)*NM+j];
    float cc2 = C2[(b*NR+r)*NM+j], cc3 = C3[(b*NR+r)*NM+j];
    float grj = rwv[r];
    float fwd = F - Ljj*grj*(1.0f-2.0f*wwj) + wwj*(scal[r] - pj*grj);
    float bwd = (cc2 - cc3) - Ljj*grj*(1.0f-wwj) - wwj*(cc2 - Ljj*grj) + pj*(scal[4+r] - wwj*grj);
    nrw[r][j] = rm[r][0]*bwd + rm[r][1]*fwd + rm[r][2]*cw[r];
  }
  __syncthreads();
  // read_vectors
  int w = lane;
  float erw = er[w], wvw = wvec[w];
  float acc[NR]={0,0,0,0};
  int jbase = wv*64;
  for(int jj=0;jj<64;jj++){
    int jr = jbase+jj;
    float wwr = wwb[jr];
    float nmv = fmaf(mem[((size_t)b*NM+jr)*NW + w], (1.0f - wwr*erw), wwr*wvw);
    #pragma unroll
    for(int r=0;r<NR;r++) acc[r] = fmaf(nrw[r][jr], nmv, acc[r]);
  }
  #pragma unroll
  for(int r=0;r<NR;r++) accb[wv][r][w] = acc[r];
  __syncthreads();
  if (tid < 256){
    int r = tid>>6, kk = tid&63;
    float s=0;
    for(int v=0;v<16;v++) s += accb[v][r][kk];
    out[b*NR*NW + r*NW + kk] = s;
  }
}

extern "C" void kernel_launch(void* const* d_in, const int* in_sizes, int n_in,
                              void* d_out, int out_size, void* d_ws, size_t ws_size,
                              hipStream_t stream) {
  (void)in_sizes; (void)n_in; (void)out_size; (void)ws_size;
  const float* xi   = (const float*)d_in[0];
  const float* Wm   = (const float*)d_in[1];
  const float* bW   = (const float*)d_in[2];
  const float* mem  = (const float*)d_in[3];
  const float* link = (const float*)d_in[4];
  const float* prec = (const float*)d_in[5];
  const float* rw   = (const float*)d_in[6];
  const float* wwo  = (const float*)d_in[7];
  const float* uv   = (const float*)d_in[8];
  float* out = (float*)d_out;
  float* ws  = (float*)d_ws;
  float* iface = ws;                 // 64*471 -> pad 30208
  float* wwp   = ws + 30208;         // 65536
  float* RF    = wwp + 65536;        // 262144
  float* C2    = RF + 262144;        // 262144
  float* C3    = C2 + 262144;        // 262144
  int n4 = (3*262144)/4;             // RF,C2,C3 zero-init as float4
  k_zero<<<(n4+255)/256, 256, 0, stream>>>((float4*)RF, n4);
  k_iface<<<NB, 256, 0, stream>>>(xi, Wm, bW, iface);
  k_write<<<NB, 1024, 0, stream>>>(iface, mem, rw, wwo, uv, wwp);
  k_link5<<<dim3(4, 4, NB), 256, 0, stream>>>(link, rw, wwp, RF, C2, C3);
  k_read<<<NB, 1024, 0, stream>>>(iface, mem, link, prec, rw, wwp, RF, C2, C3, out);
}

// Round 9
// 162.348 us; speedup vs baseline: 2.7102x; 1.2400x over previous
//
#include <hip/hip_runtime.h>

#define DELTA 1e-6f

// sizes: b=64, m=1024, w=64, r=4, d=512, iface=471
#define NB 64
#define NM 1024
#define NW 64
#define NR 4
#define ND 512
#define NIF 471

typedef unsigned long long ull;

__device__ __forceinline__ float sigmoidf_(float x){ return 1.0f/(1.0f+expf(-x)); }
__device__ __forceinline__ float softplusf_(float x){ return fmaxf(x,0.0f) + log1pf(expf(-fabsf(x))); }

__device__ __forceinline__ float waveSum(float v){
  #pragma unroll
  for(int o=32;o>0;o>>=1) v += __shfl_down(v,o,64);
  return v;
}
__device__ __forceinline__ float waveMax(float v){
  #pragma unroll
  for(int o=32;o>0;o>>=1) v = fmaxf(v, __shfl_down(v,o,64));
  return v;
}
__device__ __forceinline__ ull shflxor64(ull k, int m){
  unsigned lo = (unsigned)(k & 0xffffffffu), hi = (unsigned)(k>>32);
  lo = (unsigned)__shfl_xor((int)lo, m, 64);
  hi = (unsigned)__shfl_xor((int)hi, m, 64);
  return ((ull)hi<<32)|lo;
}

// ---------------- K0: zero the output (k_readb accumulates into it) ----------------
__global__ __launch_bounds__(256) void k_zero(float4* __restrict__ p, int n4){
  int i = blockIdx.x*256 + threadIdx.x;
  if (i < n4) p[i] = make_float4(0.f,0.f,0.f,0.f);
}

// ---------------- K1: iface = xi @ W + bW (128 blocks) ----------------
__global__ __launch_bounds__(256) void k_iface(const float* __restrict__ xi,
                                               const float* __restrict__ Wm,
                                               const float* __restrict__ bW,
                                               float* __restrict__ iface){
  int b = blockIdx.x, half = blockIdx.y;
  __shared__ float xs[ND];
  for(int k=threadIdx.x;k<ND;k+=256) xs[k]=xi[b*ND+k];
  __syncthreads();
  int c = half*236 + threadIdx.x;
  int cend = half ? NIF : 236;
  if (c < cend){
    float acc = bW[c];
    #pragma unroll 4
    for(int k=0;k<ND;k++) acc = fmaf(xs[k], Wm[k*NIF+c], acc);
    iface[b*NIF+c]=acc;
  }
}

// ---------------- K1b: full-GPU pass over mem for write-content dot/nrm + usage ----------------
// (was inside 64-block k_write: 16MB mem pass at 25% of CUs; now 256 blocks)
__global__ __launch_bounds__(256) void k_wcos(
    const float* __restrict__ iface, const float* __restrict__ mem,
    const float* __restrict__ rw_old, const float* __restrict__ ww_old,
    const float* __restrict__ uv,
    float* __restrict__ uu, float* __restrict__ wcd, float* __restrict__ wcn){
  int b = blockIdx.y;
  int j = blockIdx.x*256 + threadIdx.x;
  __shared__ float wkey[NW];
  const float* ifb = iface + b*NIF;
  if (threadIdx.x < NW) wkey[threadIdx.x] = ifb[260+threadIdx.x];
  __syncthreads();
  float fg0=sigmoidf_(ifb[453]), fg1=sigmoidf_(ifb[454]);
  float fg2=sigmoidf_(ifb[455]), fg3=sigmoidf_(ifb[456]);
  float u0  = uv[b*NM+j];
  float wwo = ww_old[b*NM+j];
  float usage = u0 + (1.0f-u0)*wwo;
  float psi = (1.0f - fg0*rw_old[(b*NR+0)*NM+j])
            * (1.0f - fg1*rw_old[(b*NR+1)*NM+j])
            * (1.0f - fg2*rw_old[(b*NR+2)*NM+j])
            * (1.0f - fg3*rw_old[(b*NR+3)*NM+j]);
  usage *= psi;
  uu[b*NM+j] = DELTA + (1.0f-DELTA)*usage;
  float dot=0.0f, nrm=0.0f;
  const float4* mrow4 = (const float4*)(mem + ((size_t)b*NM + j)*NW);
  #pragma unroll 4
  for(int k=0;k<16;k++){
    float4 mv = mrow4[k];
    const float* wk = wkey + k*4;
    dot = fmaf(mv.x,wk[0],dot); dot = fmaf(mv.y,wk[1],dot);
    dot = fmaf(mv.z,wk[2],dot); dot = fmaf(mv.w,wk[3],dot);
    nrm = fmaf(mv.x,mv.x,nrm); nrm = fmaf(mv.y,mv.y,nrm);
    nrm = fmaf(mv.z,mv.z,nrm); nrm = fmaf(mv.w,mv.w,nrm);
  }
  wcd[b*NM+j]=dot; wcn[b*NM+j]=nrm;
}

// ---------------- K2: softmax + bitonic sort + cumprod + new_write_w (sort-only now) ----------------
__global__ __launch_bounds__(1024) void k_write2(
    const float* __restrict__ iface, const float* __restrict__ uu,
    const float* __restrict__ wcd, const float* __restrict__ wcn,
    float* __restrict__ wwp){
  int b = blockIdx.x; int tid = threadIdx.x;
  int lane = tid & 63, wv = tid >> 6;
  __shared__ float wkey[NW];
  __shared__ ull skA[NM];
  __shared__ ull skB[NM];
  __shared__ float fb2[NM];
  __shared__ float red[17];
  __shared__ float s_wp[16], s_wp2[16];
  const float* ifb = iface + b*NIF;
  if (tid < NW) wkey[tid] = ifb[260+tid];
  __syncthreads();
  float sw = softplusf_(1.0f + fmaxf(ifb[324],0.0f));
  float ag = sigmoidf_(ifb[457]);
  float wg = sigmoidf_(ifb[458]);
  float kn=0.0f;
  for(int k=0;k<NW;k++){ float t=wkey[k]; kn += t*t; }
  kn = sqrtf(kn);
  float logit = sw * wcd[b*NM+tid] / ((sqrtf(wcn[b*NM+tid])+DELTA)*(kn+DELTA));
  float m1 = waveMax(logit); if(lane==0) red[wv]=m1; __syncthreads();
  if(tid==0){ float mm=red[0]; for(int i=1;i<16;i++) mm=fmaxf(mm,red[i]); red[16]=mm; } __syncthreads();
  float e = expf(logit - red[16]);
  float s1 = waveSum(e); if(lane==0) red[wv]=s1; __syncthreads();
  if(tid==0){ float ss=0; for(int i=0;i<16;i++) ss+=red[i]; red[16]=ss; } __syncthreads();
  float wcw = e/red[16];
  // ---- bitonic sort of (u, idx): strides<64 via shfl, >=64 via ping-pong LDS ----
  float u = uu[b*NM+tid];
  ull k = ((ull)__float_as_uint(u) << 32) | (unsigned)tid;
  bool useA = true;
  for (int k2=2; k2<=NM; k2<<=1){
    for (int jj=k2>>1; jj>0; jj>>=1){
      ull p;
      if (jj >= 64){
        ull* buf = useA ? skA : skB;
        buf[tid] = k;
        __syncthreads();
        p = buf[tid^jj];
        useA = !useA;
      } else {
        p = shflxor64(k, jj);
      }
      bool lower = (tid & jj) == 0;
      bool asc   = (tid & k2) == 0;
      bool takeMin = (lower == asc);
      k = takeMin ? (k<p ? k : p) : (k>p ? k : p);
    }
  }
  float su = __uint_as_float((unsigned)(k>>32));
  int phi  = (int)(k & 0xffffffffu);
  // ---- inclusive cumprod: wave scan + cross-wave prefix ----
  float sc = su;
  #pragma unroll
  for (int off=1; off<64; off<<=1){
    float t = __shfl_up(sc, off, 64);
    if (lane >= off) sc *= t;
  }
  if (lane==63) s_wp[wv] = sc;
  __syncthreads();
  if (tid==0){
    float p=1.0f;
    for (int w=0;w<16;w++){ float t=s_wp[w]; s_wp2[w]=p; p*=t; }
  }
  __syncthreads();
  float P = sc * s_wp2[wv];
  float salloc = (1.0f - su)*P;
  fb2[phi] = salloc;
  __syncthreads();
  float alloc = fb2[tid];
  wwp[b*NM+tid] = wg*(ag*alloc + (1.0f-ag)*wcw);
}

// ---------------- K3: one streaming pass over L -> DISJOINT partial buffers (no atomics) ----------------
// Block (cx,ry,b): 256 rows x 256 cols, 8 chunks of 32 rows in LDS (40.5KB -> 3-4 blocks/CU).
// RFp[cx][b,r,row]  (each (cx,ry,b) owns rows ry*256..+256 of slice cx -> written once, plain stores)
// C2p/C3p[ry][b,r,col] (block owns cols cx*256..+256 of slice ry)
// Diagonal blocks (cx==ry) also export ldiag[b,row] from staged LDS (kills scattered diag reads later).
// Round 3-5 lesson: keep live set ~60 VGPR (spill-proof); rounds 6-8: 1.5M global atomics removed here.
__global__ __launch_bounds__(256) void k_link6(
    const float* __restrict__ link, const float* __restrict__ rw,
    const float* __restrict__ wwp,
    float* __restrict__ RFp, float* __restrict__ C2p, float* __restrict__ C3p,
    float* __restrict__ ldiag){
  int cx = blockIdx.x, ry = blockIdx.y, b = blockIdx.z;
  int tid = threadIdx.x, lane = tid&63, wv = tid>>6;
  __shared__ float4 s_L4[32*64];   // 32KB
  __shared__ float4 s_gcol4[256];  // 4KB {g0..g3} per col
  __shared__ float  s_mwc[256];    // 1KB: 1-ww[col]
  __shared__ float4 s_grow4[32];
  __shared__ float  s_wwr[32];
  __shared__ float4 s_rfp4[128];
  const float* Lb = link + ((size_t)b<<20);
  int colbase = cx*256, rowbase = ry*256;
  {
    float g0 = rw[(b*NR+0)*NM + colbase + tid];
    float g1 = rw[(b*NR+1)*NM + colbase + tid];
    float g2 = rw[(b*NR+2)*NM + colbase + tid];
    float g3 = rw[(b*NR+3)*NM + colbase + tid];
    s_gcol4[tid] = make_float4(g0,g1,g2,g3);
    s_mwc[tid] = 1.0f - wwp[b*NM + colbase + tid];
  }
  float c2a[NR][4], c3a[NR][4];
  #pragma unroll
  for(int r=0;r<NR;r++){
    #pragma unroll
    for(int e=0;e<4;e++){ c2a[r][e]=0.0f; c3a[r][e]=0.0f; }
  }
  for (int ch=0; ch<8; ++ch){
    int rb = rowbase + ch*32;
    if (tid < 128) ((float*)s_grow4)[tid] = rw[(b*NR+(tid&3))*NM + rb + (tid>>2)];
    if (tid < 32)  s_wwr[tid] = wwp[b*NM + rb + tid];
    #pragma unroll
    for (int jq=0;jq<8;jq++){
      int rl = wv + 4*jq;
      float4 lv = *(const float4*)(Lb + (size_t)(rb+rl)*NM + colbase + lane*4);
      s_L4[rl*64 + (lane ^ (rl&7))] = lv;
    }
    __syncthreads();
    // diag export (cx==ry blocks contain the diagonal of this row range)
    if (cx == ry && tid < 32){
      int coff = ch*32 + tid;
      float4 v = s_L4[tid*64 + ((coff>>2) ^ (tid&7))];
      float d = (coff&1) ? ((coff&2)? v.w : v.y) : ((coff&2)? v.z : v.x);
      ldiag[b*NM + rb + tid] = d;
    }
    // ---- phase R: row = lane&31, half h = lane>>5; wave covers 64 cols ----
    {
      int row = lane&31, h = lane>>5, row7 = row&7;
      float wwj = s_wwr[row];
      float rf[4] = {0,0,0,0};
      #pragma unroll 2
      for (int i=0;i<8;i++){
        int cb = wv*16 + h*8 + i;
        float4 lv = s_L4[row*64 + (cb ^ row7)];
        float4 mw = ((const float4*)s_mwc)[cb];
        float le[4] = {lv.x,lv.y,lv.z,lv.w};
        float mv[4] = {mw.x,mw.y,mw.z,mw.w};
        #pragma unroll
        for (int e=0;e<4;e++){
          float4 gv = s_gcol4[cb*4+e];
          float ls = le[e]*(mv[e]-wwj);
          rf[0] = fmaf(ls, gv.x, rf[0]);
          rf[1] = fmaf(ls, gv.y, rf[1]);
          rf[2] = fmaf(ls, gv.z, rf[2]);
          rf[3] = fmaf(ls, gv.w, rf[3]);
        }
      }
      #pragma unroll
      for (int r=0;r<NR;r++) rf[r] += __shfl_xor(rf[r], 32, 64);
      if (lane < 32) s_rfp4[wv*32+row] = make_float4(rf[0],rf[1],rf[2],rf[3]);
    }
    // ---- phase C: wave covers 8 rows, lane owns 4 cols ----
    #pragma unroll 2
    for (int ri=0; ri<8; ri++){
      int row = wv*8 + ri;
      float4 lv = s_L4[row*64 + (lane ^ (row&7))];
      float4 gg = s_grow4[row];
      float wwr = s_wwr[row];
      float le[4] = {lv.x,lv.y,lv.z,lv.w};
      float ggv[4] = {gg.x,gg.y,gg.z,gg.w};
      float ggw[4];
      #pragma unroll
      for (int r=0;r<NR;r++) ggw[r] = ggv[r]*wwr;
      #pragma unroll
      for (int e=0;e<4;e++){
        #pragma unroll
        for (int r=0;r<NR;r++){
          c2a[r][e] = fmaf(le[e], ggv[r], c2a[r][e]);
          c3a[r][e] = fmaf(le[e], ggw[r], c3a[r][e]);
        }
      }
    }
    __syncthreads();
    if (tid < 128){
      int row = tid>>2, r = tid&3;
      float s = ((const float*)&s_rfp4[0*32+row])[r] + ((const float*)&s_rfp4[1*32+row])[r]
              + ((const float*)&s_rfp4[2*32+row])[r] + ((const float*)&s_rfp4[3*32+row])[r];
      RFp[((size_t)cx<<18) + (b*NR+r)*NM + rb + row] = s;
    }
  }
  // ---- c2/c3 cross-wave combine (reuse s_L4), plain float4 stores to own slice ----
  __syncthreads();
  float4* s_comb = s_L4;
  #pragma unroll
  for (int r=0;r<NR;r++){
    s_comb[(wv*64+lane)*8 + r]     = make_float4(c2a[r][0],c2a[r][1],c2a[r][2],c2a[r][3]);
    s_comb[(wv*64+lane)*8 + 4 + r] = make_float4(c3a[r][0],c3a[r][1],c3a[r][2],c3a[r][3]);
  }
  __syncthreads();
  for (int t=tid; t<512; t+=256){
    int lc = t>>3, q = t&7;
    float4 a = s_comb[(0*64+lc)*8+q];
    float4 bb= s_comb[(1*64+lc)*8+q];
    float4 c = s_comb[(2*64+lc)*8+q];
    float4 d = s_comb[(3*64+lc)*8+q];
    float4 s = make_float4(a.x+bb.x+c.x+d.x, a.y+bb.y+c.y+d.y, a.z+bb.z+c.z+d.z, a.w+bb.w+c.w+d.w);
    float* dst = (q<4) ? &C2p[((size_t)ry<<18) + (b*NR+q)*NM + colbase + lc*4]
                       : &C3p[((size_t)ry<<18) + (b*NR+(q-4))*NM + colbase + lc*4];
    *(float4*)dst = s;
  }
}

// ---------------- K3b: combine the 4 partial slices -> RF, C2, C3 ----------------
__global__ __launch_bounds__(256) void k_comb(
    const float* __restrict__ RFp, const float* __restrict__ C2p, const float* __restrict__ C3p,
    float* __restrict__ RF, float* __restrict__ C2, float* __restrict__ C3){
  int idx = blockIdx.x*256 + threadIdx.x;   // grid 1024 -> 262144
  RF[idx] = RFp[idx] + RFp[(1<<18)+idx] + RFp[(2<<18)+idx] + RFp[(3<<18)+idx];
  C2[idx] = C2p[idx] + C2p[(1<<18)+idx] + C2p[(2<<18)+idx] + C2p[(3<<18)+idx];
  C3[idx] = C3p[idx] + C3p[(1<<18)+idx] + C3p[(2<<18)+idx] + C3p[(3<<18)+idx];
}

// ---------------- K4a: full-GPU pass over mem for read-content dots/nrm (new_memory on the fly) ----------------
__global__ __launch_bounds__(256) void k_rdots(
    const float* __restrict__ iface, const float* __restrict__ mem,
    const float* __restrict__ wwp, float* __restrict__ dots){
  int b = blockIdx.y;
  int j = blockIdx.x*256 + threadIdx.x;
  __shared__ float keys[NR][NW];
  __shared__ float er[NW], wvec[NW];
  const float* ifb = iface + b*NIF;
  { int r=threadIdx.x>>6, kk=threadIdx.x&63; keys[r][kk] = ifb[r*NW+kk]; }
  if (threadIdx.x < 64) er[threadIdx.x] = sigmoidf_(ifb[325+threadIdx.x]);
  else if (threadIdx.x < 128) wvec[threadIdx.x-64] = ifb[389+threadIdx.x-64];
  __syncthreads();
  float wwj = wwp[b*NM+j];
  const float* mrow = mem + ((size_t)b*NM+j)*NW;
  float dt[NR]={0,0,0,0}; float nrm=0.0f;
  for(int k=0;k<NW;k++){
    float nmv = fmaf(mrow[k], (1.0f - wwj*er[k]), wwj*wvec[k]);
    nrm = fmaf(nmv,nmv,nrm);
    #pragma unroll
    for(int r=0;r<NR;r++) dt[r] = fmaf(nmv, keys[r][k], dt[r]);
  }
  #pragma unroll
  for(int r=0;r<NR;r++) dots[(b*5+r)*NM + j] = dt[r];
  dots[(b*5+4)*NM + j] = nrm;
}

// ---------------- K4b: Pr/Kr + read softmax + fwd/bwd finalize -> nrw ----------------
__global__ __launch_bounds__(1024) void k_rmid(
    const float* __restrict__ iface, const float* __restrict__ prec,
    const float* __restrict__ rw_old, const float* __restrict__ wwp,
    const float* __restrict__ dots, const float* __restrict__ ldiag,
    const float* __restrict__ RF, const float* __restrict__ C2, const float* __restrict__ C3,
    float* __restrict__ nrwg){
  int b = blockIdx.x; int tid = threadIdx.x; int lane=tid&63, wv=tid>>6;
  __shared__ float s_pk[16][8];
  __shared__ float scal[16];   // [0..3]=Pr, [4..7]=Kr, [8..11]=keynorm, [12..15]=strength
  __shared__ float smax[NR], ssum[NR];
  __shared__ float rm[NR][3];
  const float* ifb = iface + b*NIF;
  if (tid == 0){
    for(int mo=0;mo<3;mo++){
      float x0=ifb[458+0*3+mo], x1=ifb[458+1*3+mo], x2=ifb[458+2*3+mo], x3=ifb[458+3*3+mo];
      float mx = fmaxf(fmaxf(x0,x1),fmaxf(x2,x3));
      float e0=expf(x0-mx),e1=expf(x1-mx),e2=expf(x2-mx),e3=expf(x3-mx);
      float s=e0+e1+e2+e3;
      rm[0][mo]=e0/s; rm[1][mo]=e1/s; rm[2][mo]=e2/s; rm[3][mo]=e3/s;
    }
  }
  if (tid >= 320 && tid < 324){
    int r = tid-320;
    float knv=0;
    for(int k=0;k<NW;k++){ float t=ifb[r*NW+k]; knv += t*t; }
    scal[8+r]  = sqrtf(knv);
    scal[12+r] = softplusf_(1.0f + fmaxf(ifb[256+r],0.0f));
  }
  __syncthreads();
  int j = tid;
  float pj  = prec[b*NM+j];
  float wwj = wwp[b*NM+j];
  float rwv[NR];
  #pragma unroll
  for(int r=0;r<NR;r++) rwv[r]=rw_old[(b*NR+r)*NM+j];
  {
    float v8[8];
    #pragma unroll
    for(int r=0;r<NR;r++){ v8[r] = pj*rwv[r]; v8[4+r] = wwj*rwv[r]; }
    #pragma unroll
    for(int q=0;q<8;q++){
      float s = waveSum(v8[q]);
      if(lane==0) s_pk[wv][q]=s;
    }
    __syncthreads();
    if (tid < 8){
      float ss=0;
      for(int w=0;w<16;w++) ss += s_pk[w][tid];
      scal[tid]=ss;
    }
    __syncthreads();
  }
  float dt[NR];
  #pragma unroll
  for(int r=0;r<NR;r++) dt[r] = dots[(b*5+r)*NM + j];
  float nrm = dots[(b*5+4)*NM + j];
  float inv = 1.0f/(sqrtf(nrm)+DELTA);
  float logit[NR], ce[NR], cw[NR];
  #pragma unroll
  for(int r=0;r<NR;r++) logit[r] = scal[12+r]*dt[r]*inv/(scal[8+r]+DELTA);
  #pragma unroll
  for(int r=0;r<NR;r++){
    float m1 = waveMax(logit[r]);
    if(lane==0) s_pk[wv][r]=m1;
  }
  __syncthreads();
  if (tid < NR){
    float mm=s_pk[0][tid];
    for(int w=1;w<16;w++) mm=fmaxf(mm,s_pk[w][tid]);
    smax[tid]=mm;
  }
  __syncthreads();
  #pragma unroll
  for(int r=0;r<NR;r++){
    ce[r] = expf(logit[r]-smax[r]);
    float s1 = waveSum(ce[r]);
    if(lane==0) s_pk[wv][r]=s1;
  }
  __syncthreads();
  if (tid < NR){
    float ss=0;
    for(int w=0;w<16;w++) ss += s_pk[w][tid];
    ssum[tid]=ss;
  }
  __syncthreads();
  #pragma unroll
  for(int r=0;r<NR;r++) cw[r] = ce[r]/ssum[r];
  float Ljj = ldiag[b*NM+j];
  #pragma unroll
  for(int r=0;r<NR;r++){
    float F   = RF[(b*NR+r)*NM+j];
    float cc2 = C2[(b*NR+r)*NM+j], cc3 = C3[(b*NR+r)*NM+j];
    float grj = rwv[r];
    float fwd = F - Ljj*grj*(1.0f-2.0f*wwj) + wwj*(scal[r] - pj*grj);
    float bwd = (cc2 - cc3) - Ljj*grj*(1.0f-wwj) - wwj*(cc2 - Ljj*grj) + pj*(scal[4+r] - wwj*grj);
    nrwg[(b*NR+r)*NM+j] = rm[r][0]*bwd + rm[r][1]*fwd + rm[r][2]*cw[r];
  }
}

// ---------------- K4c: read_vectors = nrw @ new_memory, 256-block partial matmul ----------------
__global__ __launch_bounds__(256) void k_readb(
    const float* __restrict__ iface, const float* __restrict__ mem,
    const float* __restrict__ wwp, const float* __restrict__ nrwg,
    float* __restrict__ out){
  int jt = blockIdx.x, b = blockIdx.y;
  int tid = threadIdx.x, lane = tid&63, wv = tid>>6;
  __shared__ float s_nrw[NR][256];
  __shared__ float s_ww[256];
  __shared__ float s_er[NW], s_wv[NW];
  __shared__ float s_acc[4][NR][NW];
  const float* ifb = iface + b*NIF;
  int j0 = jt*256;
  #pragma unroll
  for(int r=0;r<NR;r++) s_nrw[r][tid] = nrwg[(b*NR+r)*NM + j0+tid];
  s_ww[tid] = wwp[b*NM + j0+tid];
  if (tid < 64) s_er[tid] = sigmoidf_(ifb[325+tid]);
  else if (tid < 128) s_wv[tid-64] = ifb[389+tid-64];
  __syncthreads();
  int w = lane;
  float erw = s_er[w], wvw = s_wv[w];
  float acc[NR]={0,0,0,0};
  for(int jj=0;jj<64;jj++){
    int jl = wv*64+jj;
    float wwr = s_ww[jl];
    float nmv = fmaf(mem[((size_t)b*NM + j0+jl)*NW + w], (1.0f - wwr*erw), wwr*wvw);
    #pragma unroll
    for(int r=0;r<NR;r++) acc[r] = fmaf(s_nrw[r][jl], nmv, acc[r]);
  }
  #pragma unroll
  for(int r=0;r<NR;r++) s_acc[wv][r][w] = acc[r];
  __syncthreads();
  {
    int r = tid>>6, k = tid&63;
    float s = s_acc[0][r][k]+s_acc[1][r][k]+s_acc[2][r][k]+s_acc[3][r][k];
    atomicAdd(&out[b*NR*NW + r*NW + k], s);
  }
}

extern "C" void kernel_launch(void* const* d_in, const int* in_sizes, int n_in,
                              void* d_out, int out_size, void* d_ws, size_t ws_size,
                              hipStream_t stream) {
  (void)in_sizes; (void)n_in; (void)out_size; (void)ws_size;
  const float* xi   = (const float*)d_in[0];
  const float* Wm   = (const float*)d_in[1];
  const float* bW   = (const float*)d_in[2];
  const float* mem  = (const float*)d_in[3];
  const float* link = (const float*)d_in[4];
  const float* prec = (const float*)d_in[5];
  const float* rw   = (const float*)d_in[6];
  const float* wwo  = (const float*)d_in[7];
  const float* uv   = (const float*)d_in[8];
  float* out = (float*)d_out;
  float* ws  = (float*)d_ws;
  float* iface = ws;                  // 30208
  float* wwp   = ws + 30208;          // 65536
  float* uu    = ws + 95744;          // 65536
  float* wcd   = ws + 161280;         // 65536
  float* wcn   = ws + 226816;         // 65536
  float* dots  = ws + 292352;         // 327680 = [b][5][1024]
  float* ldiag = ws + 620032;         // 65536
  float* nrwg  = ws + 685568;         // 262144
  float* RF    = ws + 947712;         // 262144
  float* C2    = ws + 1209856;        // 262144
  float* C3    = ws + 1472000;        // 262144
  float* RFp   = ws + 1734144;        // 4*262144
  float* C2p   = ws + 2782720;        // 4*262144
  float* C3p   = ws + 3831296;        // 4*262144  (total ~18.6MB of the 1GB ws)
  k_zero <<<16, 256, 0, stream>>>((float4*)out, 4096);
  k_iface<<<dim3(NB,2), 256, 0, stream>>>(xi, Wm, bW, iface);
  k_wcos <<<dim3(4,NB), 256, 0, stream>>>(iface, mem, rw, wwo, uv, uu, wcd, wcn);
  k_write2<<<NB, 1024, 0, stream>>>(iface, uu, wcd, wcn, wwp);
  k_link6<<<dim3(4,4,NB), 256, 0, stream>>>(link, rw, wwp, RFp, C2p, C3p, ldiag);
  k_comb <<<1024, 256, 0, stream>>>(RFp, C2p, C3p, RF, C2, C3);
  k_rdots<<<dim3(4,NB), 256, 0, stream>>>(iface, mem, wwp, dots);
  k_rmid <<<NB, 1024, 0, stream>>>(iface, prec, rw, wwp, dots, ldiag, RF, C2, C3, nrwg);
  k_readb<<<dim3(4,NB), 256, 0, stream>>>(iface, mem, wwp, nrwg, out);
}